// Round 2
// baseline (4449.506 us; speedup 1.0000x reference)
//
#include <hip/hip_runtime.h>
#include <cstddef>

// ---- problem dims ----
#define Bq    16
#define Lq    512
#define Mq    32
#define PREDq 96
#define Pq    16
#define Sq    8
#define Dq    128
#define NSTq  16
#define DCq   4
#define NLq   4
#define Nq    63
#define DIq   256
#define DTRq  8
#define TOKq  32256   // 512*63 == 1008*32
#define BMq   512
#define BNq   1008

// ---- workspace layout (float offsets) ----
// total = 63,271,936 floats = 241.4 MiB  (fits 256 MiB workspace)
constexpr size_t HSZ       = (size_t)TOKq * Dq;            // 4,128,768
constexpr size_t OFF_MEANS = 0;
constexpr size_t OFF_STDS  = 512;
constexpr size_t OFF_HEAD  = 1024;                          // 512*96
constexpr size_t OFF_HIST  = 50176;                         // 9 hist buffers
constexpr size_t OFF_MIX   = OFF_HIST + 9 * HSZ;
constexpr size_t OFF_LN    = OFF_MIX + HSZ;
constexpr size_t OFF_XZ    = OFF_LN + HSZ;                  // TOK x 512
constexpr size_t OFF_XD    = OFF_XZ + (size_t)TOKq * 512;   // TOK x 40
constexpr size_t WS_FLOATS = OFF_XD + (size_t)TOKq * 40;

__device__ __forceinline__ float silu_f(float v) { return v / (1.f + __expf(-v)); }

// ============ stats: per (b,m) mean / unbiased std over L ============
__global__ __launch_bounds__(256) void stats_kernel(const float* __restrict__ x,
                                                    float* __restrict__ means,
                                                    float* __restrict__ stds) {
    int bm = blockIdx.x; int b = bm >> 5, m = bm & 31;
    int tid = threadIdx.x;
    float s = 0.f, ss = 0.f;
    for (int l = tid; l < Lq; l += 256) {
        float v = x[((size_t)b * Lq + l) * Mq + m];
        s += v; ss += v * v;
    }
#pragma unroll
    for (int o = 32; o >= 1; o >>= 1) { s += __shfl_xor(s, o); ss += __shfl_xor(ss, o); }
    __shared__ float sh0[4], sh1[4];
    if ((tid & 63) == 0) { sh0[tid >> 6] = s; sh1[tid >> 6] = ss; }
    __syncthreads();
    if (tid == 0) {
        float S  = sh0[0] + sh0[1] + sh0[2] + sh0[3];
        float SS = sh1[0] + sh1[1] + sh1[2] + sh1[3];
        float mean = S * (1.f / (float)Lq);
        float var  = (SS - (float)Lq * mean * mean) * (1.f / (float)(Lq - 1));
        means[bm] = mean;
        stds[bm]  = sqrtf(fmaxf(var, 0.f)) + 1e-5f;
    }
}

// ============ patch embed: h[bm,n,d] ============
__global__ __launch_bounds__(128) void patch_embed(const float* __restrict__ x,
                                                   const float* __restrict__ means,
                                                   const float* __restrict__ stds,
                                                   const float* __restrict__ pw,
                                                   const float* __restrict__ pb,
                                                   const float* __restrict__ pos,
                                                   float* __restrict__ h) {
    int blk = blockIdx.x;
    int bm = blk / Nq, n = blk - bm * Nq;
    int b = bm >> 5, m = bm & 31;
    int d = threadIdx.x;
    __shared__ float sx[Pq];
    if (d < Pq) {
        int l = n * Sq + d;
        sx[d] = (x[((size_t)b * Lq + l) * Mq + m] - means[bm]) / stds[bm];
    }
    __syncthreads();
    float acc = pb[d];
#pragma unroll
    for (int p = 0; p < Pq; p++) acc += sx[p] * pw[d * Pq + p];
    h[(size_t)blk * Dq + d] = acc + pos[n * Dq + d];
}

// ============ generic GEMM: C(M,N) = A(M,K) @ B(N,K)^T (+bias)(+resid)(accum) ============
// rowmap==1: output row gm (channel layout (b*N+n)*M+m) is remapped to token
// layout (b*M+m)*N+n for both resid read and C write.
__global__ __launch_bounds__(256) void gemm_tn(const float* __restrict__ A, int lda,
                                               const float* __restrict__ B, int ldb,
                                               const float* __restrict__ bias,
                                               const float* __restrict__ resid, int ldr,
                                               float* __restrict__ C, int ldc,
                                               int M, int N, int K, int accum, int rowmap) {
    __shared__ __align__(16) float As[16][68];
    __shared__ __align__(16) float Bs[16][68];
    int tid = threadIdx.x;
    int tx = tid & 15, ty = tid >> 4;
    int m0 = blockIdx.y * 64, n0 = blockIdx.x * 64;
    float acc[4][4] = {};
    for (int k0 = 0; k0 < K; k0 += 16) {
#pragma unroll
        for (int i = 0; i < 4; i++) {
            int id = tid + 256 * i;
            int kk = id & 15, mn = id >> 4;
            int gk = k0 + kk;
            int gm = m0 + mn;
            As[kk][mn] = (gm < M) ? A[(size_t)gm * lda + gk] : 0.f;
            int gn = n0 + mn;
            Bs[kk][mn] = (gn < N) ? B[(size_t)gn * ldb + gk] : 0.f;
        }
        __syncthreads();
#pragma unroll
        for (int kk = 0; kk < 16; kk++) {
            float av[4], bv[4];
#pragma unroll
            for (int i = 0; i < 4; i++) av[i] = As[kk][ty * 4 + i];
#pragma unroll
            for (int j = 0; j < 4; j++) bv[j] = Bs[kk][tx * 4 + j];
#pragma unroll
            for (int i = 0; i < 4; i++)
#pragma unroll
                for (int j = 0; j < 4; j++) acc[i][j] += av[i] * bv[j];
        }
        __syncthreads();
    }
#pragma unroll
    for (int i = 0; i < 4; i++) {
        int gm = m0 + ty * 4 + i;
        if (gm >= M) continue;
        int orow = gm;
        if (rowmap) {
            int bn = gm >> 5, m = gm & 31;       // gm = (b*N+n)*M + m, M=32
            int b = bn / Nq, n = bn - b * Nq;
            orow = (b * Mq + m) * Nq + n;
        }
#pragma unroll
        for (int j = 0; j < 4; j++) {
            int gn = n0 + tx * 4 + j;
            if (gn >= N) continue;
            float v = acc[i][j];
            if (bias)  v += bias[gn];
            if (resid) v += resid[(size_t)orow * ldr + gn];
            size_t o = (size_t)orow * ldc + gn;
            if (accum) C[o] += v; else C[o] = v;
        }
    }
}

// ============ in-place causal depthwise conv (DC=4) + SiLU on xz cols 0..255 ============
__global__ __launch_bounds__(256) void conv_silu(float* __restrict__ xz,
                                                 const float* __restrict__ cw,
                                                 const float* __restrict__ cb,
                                                 int nb, int slen, int rev) {
    int idx = blockIdx.x * 256 + threadIdx.x;
    if (idx >= nb * DIq) return;
    int row = idx >> 8, c = idx & 255;
    float w0 = cw[c * 4 + 0], w1 = cw[c * 4 + 1], w2 = cw[c * 4 + 2], w3 = cw[c * 4 + 3];
    float bv = cb[c];
    float a = 0.f, bq = 0.f, cq = 0.f;
    if (!rev) {
        for (int s = 0; s < slen; s++) {
            size_t o = ((size_t)row * slen + s) * 512 + c;
            float xc = xz[o];
            float v = w0 * a + w1 * bq + w2 * cq + w3 * xc + bv;
            xz[o] = silu_f(v);
            a = bq; bq = cq; cq = xc;
        }
    } else {
        for (int s = slen - 1; s >= 0; s--) {
            size_t o = ((size_t)row * slen + s) * 512 + c;
            float xc = xz[o];
            float v = w0 * a + w1 * bq + w2 * cq + w3 * xc + bv;
            xz[o] = silu_f(v);
            a = bq; bq = cq; cq = xc;
        }
    }
}

// ============ fused dt_proj + softplus + selective scan + D skip + z gate ============
__global__ __launch_bounds__(256) void scan_kernel(float* __restrict__ xz,
                                                   const float* __restrict__ xd,
                                                   const float* __restrict__ dtw,
                                                   const float* __restrict__ dtb,
                                                   const float* __restrict__ alog,
                                                   const float* __restrict__ Dp,
                                                   int slen, int rev) {
    int row = blockIdx.x;
    int d = threadIdx.x;
    __shared__ float sh[40];
    float A[16], h[16];
#pragma unroll
    for (int j = 0; j < 16; j++) { A[j] = -__expf(alog[d * 16 + j]); h[j] = 0.f; }
    float dw[8];
#pragma unroll
    for (int r = 0; r < 8; r++) dw[r] = dtw[d * 8 + r];
    float dbv = dtb[d], Dv = Dp[d];
    for (int st = 0; st < slen; st++) {
        int s = rev ? (slen - 1 - st) : st;
        size_t t = (size_t)row * slen + s;
        __syncthreads();
        if (d < 40) sh[d] = xd[t * 40 + d];
        __syncthreads();
        float dtv = dbv;
#pragma unroll
        for (int r = 0; r < 8; r++) dtv += dw[r] * sh[r];
        dtv = fmaxf(dtv, 0.f) + __logf(1.f + __expf(-fabsf(dtv)));   // softplus
        size_t o = t * 512 + d;
        float uv = xz[o];
        float zv = xz[o + 256];
        float du = dtv * uv;
        float y = 0.f;
#pragma unroll
        for (int j = 0; j < 16; j++) {
            h[j] = h[j] * __expf(dtv * A[j]) + du * sh[8 + j];
            y += h[j] * sh[24 + j];
        }
        xz[o] = (y + uv * Dv) * silu_f(zv);
    }
}

// ============ token mix + LN ============
__global__ __launch_bounds__(64) void mix_ln_tok(float* __restrict__ W,
                                                 const float* __restrict__ alpha,
                                                 const float* __restrict__ beta,
                                                 const float* __restrict__ lnw,
                                                 const float* __restrict__ lnb, int l) {
    int t = blockIdx.x, d = threadIdx.x;
    int cnt = l + 1;
    float aw[4], bw[4];
    float amax = -1e30f, bmax = -1e30f;
    for (int i = 0; i < cnt; i++) {
        aw[i] = alpha[l * 4 + i]; bw[i] = beta[l * 4 + i];
        amax = fmaxf(amax, aw[i]); bmax = fmaxf(bmax, bw[i]);
    }
    float as = 0.f, bs = 0.f;
    for (int i = 0; i < cnt; i++) {
        aw[i] = __expf(aw[i] - amax); as += aw[i];
        bw[i] = __expf(bw[i] - bmax); bs += bw[i];
    }
    float ai = 1.f / as, bi = 1.f / bs;
    float v0 = 0.f, v1 = 0.f;
    for (int i = 0; i < cnt; i++) {
        const float* yt = W + OFF_HIST + (size_t)(i == 0 ? 0 : i) * HSZ + (size_t)t * 128;
        const float* yc = W + OFF_HIST + (size_t)(i == 0 ? 0 : 4 + i) * HSZ + (size_t)t * 128;
        float wa = aw[i] * ai, wb = bw[i] * bi;
        v0 += wa * yt[d]      + wb * yc[d];
        v1 += wa * yt[d + 64] + wb * yc[d + 64];
    }
    float* mix = W + OFF_MIX + (size_t)t * 128;
    mix[d] = v0; mix[d + 64] = v1;
    float s = v0 + v1, ss = v0 * v0 + v1 * v1;
#pragma unroll
    for (int o = 32; o >= 1; o >>= 1) { s += __shfl_xor(s, o); ss += __shfl_xor(ss, o); }
    float mean = s * (1.f / 128.f);
    float var  = ss * (1.f / 128.f) - mean * mean;
    float rstd = rsqrtf(var + 1e-5f);
    float* lo = W + OFF_LN + (size_t)t * 128;
    lo[d]      = (v0 - mean) * rstd * lnw[d]      + lnb[d];
    lo[d + 64] = (v1 - mean) * rstd * lnw[d + 64] + lnb[d + 64];
}

// ============ channel mix + LN + transpose to (B*N, M, D) ============
__global__ __launch_bounds__(64) void mix_ln_ch(float* __restrict__ W,
                                                const float* __restrict__ theta,
                                                const float* __restrict__ gamma,
                                                const float* __restrict__ lnw,
                                                const float* __restrict__ lnb, int l) {
    int t = blockIdx.x, d = threadIdx.x;
    int ct = l + 2, cg = l + 1;
    float tw[5], gw[4];
    float tmax = -1e30f, gmax = -1e30f;
    for (int i = 0; i < ct; i++) { tw[i] = theta[l * 5 + i]; tmax = fmaxf(tmax, tw[i]); }
    for (int i = 0; i < cg; i++) { gw[i] = gamma[l * 4 + i]; gmax = fmaxf(gmax, gw[i]); }
    float ts = 0.f, gs = 0.f;
    for (int i = 0; i < ct; i++) { tw[i] = __expf(tw[i] - tmax); ts += tw[i]; }
    for (int i = 0; i < cg; i++) { gw[i] = __expf(gw[i] - gmax); gs += gw[i]; }
    float ti = 1.f / ts, gi = 1.f / gs;
    float v0 = 0.f, v1 = 0.f;
    for (int i = 0; i < ct; i++) {
        const float* yt = W + OFF_HIST + (size_t)(i == 0 ? 0 : i) * HSZ + (size_t)t * 128;
        float w_ = tw[i] * ti;
        v0 += w_ * yt[d]; v1 += w_ * yt[d + 64];
    }
    for (int i = 0; i < cg; i++) {
        const float* yc = W + OFF_HIST + (size_t)(i == 0 ? 0 : 4 + i) * HSZ + (size_t)t * 128;
        float w_ = gw[i] * gi;
        v0 += w_ * yc[d]; v1 += w_ * yc[d + 64];
    }
    float* mix = W + OFF_MIX + (size_t)t * 128;
    mix[d] = v0; mix[d + 64] = v1;
    float s = v0 + v1, ss = v0 * v0 + v1 * v1;
#pragma unroll
    for (int o = 32; o >= 1; o >>= 1) { s += __shfl_xor(s, o); ss += __shfl_xor(ss, o); }
    float mean = s * (1.f / 128.f);
    float var  = ss * (1.f / 128.f) - mean * mean;
    float rstd = rsqrtf(var + 1e-5f);
    int bm = t / Nq, n = t - bm * Nq, b = bm >> 5, m = bm & 31;
    float* lo = W + OFF_LN + (size_t)((b * Nq + n) * Mq + m) * 128;
    lo[d]      = (v0 - mean) * rstd * lnw[d]      + lnb[d];
    lo[d + 64] = (v1 - mean) * rstd * lnw[d + 64] + lnb[d + 64];
}

// ============ channel residual: hist[5+l] += MIX (both token layout) ============
__global__ __launch_bounds__(128) void combine_ch(float* __restrict__ W, int l) {
    size_t i = (size_t)blockIdx.x * 128 + threadIdx.x;
    W[OFF_HIST + (size_t)(5 + l) * HSZ + i] += W[OFF_MIX + i];
}

// ============ plain LN over D=128 ============
__global__ __launch_bounds__(64) void ln128_kernel(const float* __restrict__ in,
                                                   const float* __restrict__ w,
                                                   const float* __restrict__ b,
                                                   float* __restrict__ out) {
    int t = blockIdx.x, d = threadIdx.x;
    float v0 = in[(size_t)t * 128 + d], v1 = in[(size_t)t * 128 + d + 64];
    float s = v0 + v1, ss = v0 * v0 + v1 * v1;
#pragma unroll
    for (int o = 32; o >= 1; o >>= 1) { s += __shfl_xor(s, o); ss += __shfl_xor(ss, o); }
    float mean = s * (1.f / 128.f);
    float var  = ss * (1.f / 128.f) - mean * mean;
    float rstd = rsqrtf(var + 1e-5f);
    out[(size_t)t * 128 + d]      = (v0 - mean) * rstd * w[d]      + b[d];
    out[(size_t)t * 128 + d + 64] = (v1 - mean) * rstd * w[d + 64] + b[d + 64];
}

// ============ LN over N=63 dimension (per (bm,d)) ============
__global__ __launch_bounds__(256) void final_ln2(const float* __restrict__ in,
                                                 const float* __restrict__ w2,
                                                 const float* __restrict__ b2,
                                                 float* __restrict__ out) {
    int idx = blockIdx.x * 256 + threadIdx.x;
    if (idx >= BMq * Dq) return;
    int bm = idx >> 7, d = idx & 127;
    float s = 0.f, ss = 0.f;
    for (int n = 0; n < Nq; n++) {
        float v = in[((size_t)bm * Nq + n) * 128 + d];
        s += v; ss += v * v;
    }
    float mean = s * (1.f / (float)Nq);
    float var  = ss * (1.f / (float)Nq) - mean * mean;
    float rstd = rsqrtf(var + 1e-5f);
    for (int n = 0; n < Nq; n++) {
        float v = in[((size_t)bm * Nq + n) * 128 + d];
        out[((size_t)bm * Nq + n) * 128 + d] = (v - mean) * rstd * w2[n] + b2[n];
    }
}

// ============ final rescale & transpose ============
__global__ __launch_bounds__(256) void finalize_kernel(const float* __restrict__ ht,
                                                       const float* __restrict__ means,
                                                       const float* __restrict__ stds,
                                                       float* __restrict__ out) {
    int idx = blockIdx.x * 256 + threadIdx.x;
    if (idx >= Bq * PREDq * Mq) return;
    int b = idx / (PREDq * Mq);
    int r = idx - b * PREDq * Mq;
    int pr = r >> 5, m = r & 31;
    int bm = b * Mq + m;
    out[idx] = ht[(size_t)bm * PREDq + pr] * stds[bm] + means[bm];
}

// ============ host-side mamba driver ============
static void run_mamba(hipStream_t stream, float* W, const float* in,
                      const float* resid, float* dst, int accum, int rowmap,
                      const float* inw, const float* cw, const float* cb,
                      const float* xw, const float* dtw, const float* dtb,
                      const float* alog, const float* Dp, const float* ow,
                      int nb, int slen, int rev) {
    int T = nb * slen;   // always 32256
    dim3 g1(512 / 64, (T + 63) / 64);
    gemm_tn<<<g1, 256, 0, stream>>>(in, 128, inw, 128, nullptr, nullptr, 0,
                                    W + OFF_XZ, 512, T, 512, 128, 0, 0);
    int thr = nb * DIq;
    conv_silu<<<(thr + 255) / 256, 256, 0, stream>>>(W + OFF_XZ, cw, cb, nb, slen, rev);
    dim3 g2(1, (T + 63) / 64);
    gemm_tn<<<g2, 256, 0, stream>>>(W + OFF_XZ, 512, xw, 256, nullptr, nullptr, 0,
                                    W + OFF_XD, 40, T, 40, 256, 0, 0);
    scan_kernel<<<nb, 256, 0, stream>>>(W + OFF_XZ, W + OFF_XD, dtw, dtb, alog, Dp, slen, rev);
    dim3 g3(2, (T + 63) / 64);
    gemm_tn<<<g3, 256, 0, stream>>>(W + OFF_XZ, 512, ow, 256, nullptr, resid, 128,
                                    dst, 128, T, 128, 256, accum, rowmap);
}

extern "C" void kernel_launch(void* const* d_in, const int* in_sizes, int n_in,
                              void* d_out, int out_size, void* d_ws, size_t ws_size,
                              hipStream_t stream) {
    if (ws_size < WS_FLOATS * sizeof(float)) return;   // diagnosable failure, not a fault

    const float* x          = (const float*)d_in[0];
    const float* patch_w    = (const float*)d_in[1];
    const float* patch_b    = (const float*)d_in[2];
    const float* pos_embed  = (const float*)d_in[3];
    const float* alpha      = (const float*)d_in[4];
    const float* beta       = (const float*)d_in[5];
    const float* theta      = (const float*)d_in[6];
    const float* gamma      = (const float*)d_in[7];
    const float* tok_norm_w = (const float*)d_in[8];
    const float* tok_norm_b = (const float*)d_in[9];
    const float* ch_norm_w  = (const float*)d_in[10];
    const float* ch_norm_b  = (const float*)d_in[11];
    const float* in_proj_w  = (const float*)d_in[12];
    const float* conv_w     = (const float*)d_in[13];
    const float* conv_b     = (const float*)d_in[14];
    const float* x_proj_w   = (const float*)d_in[15];
    const float* dt_proj_w  = (const float*)d_in[16];
    const float* dt_proj_b  = (const float*)d_in[17];
    const float* A_log      = (const float*)d_in[18];
    const float* D_ssm      = (const float*)d_in[19];
    const float* out_proj_w = (const float*)d_in[20];
    const float* n2d_w1     = (const float*)d_in[21];
    const float* n2d_b1     = (const float*)d_in[22];
    const float* n2d_w2     = (const float*)d_in[23];
    const float* n2d_b2     = (const float*)d_in[24];
    const float* head_w     = (const float*)d_in[25];
    const float* head_b     = (const float*)d_in[26];

    float* W   = (float*)d_ws;
    float* out = (float*)d_out;

    stats_kernel<<<BMq, 256, 0, stream>>>(x, W + OFF_MEANS, W + OFF_STDS);
    patch_embed<<<TOKq, 128, 0, stream>>>(x, W + OFF_MEANS, W + OFF_STDS,
                                          patch_w, patch_b, pos_embed, W + OFF_HIST);

    for (int l = 0; l < NLq; l++) {
        // ---- token mamba ----
        mix_ln_tok<<<TOKq, 64, 0, stream>>>(W, alpha, beta,
                                            tok_norm_w + l * Dq, tok_norm_b + l * Dq, l);
        {
            size_t o = (size_t)(l * 3 + 0);
            run_mamba(stream, W, W + OFF_LN, W + OFF_MIX,
                      W + OFF_HIST + (size_t)(1 + l) * HSZ, 0, 0,
                      in_proj_w + o * 512 * 128, conv_w + o * 256 * 4, conv_b + o * 256,
                      x_proj_w + o * 40 * 256, dt_proj_w + o * 256 * 8, dt_proj_b + o * 256,
                      A_log + o * 256 * 16, D_ssm + o * 256, out_proj_w + o * 128 * 256,
                      BMq, Nq, 0);
        }
        // ---- channel mamba (bidirectional), writing straight into hist[5+l] ----
        mix_ln_ch<<<TOKq, 64, 0, stream>>>(W, theta, gamma,
                                           ch_norm_w + l * Dq, ch_norm_b + l * Dq, l);
        {
            size_t o = (size_t)(l * 3 + 1);
            run_mamba(stream, W, W + OFF_LN, nullptr,
                      W + OFF_HIST + (size_t)(5 + l) * HSZ, 0, 1,
                      in_proj_w + o * 512 * 128, conv_w + o * 256 * 4, conv_b + o * 256,
                      x_proj_w + o * 40 * 256, dt_proj_w + o * 256 * 8, dt_proj_b + o * 256,
                      A_log + o * 256 * 16, D_ssm + o * 256, out_proj_w + o * 128 * 256,
                      BNq, Mq, 0);
        }
        {
            size_t o = (size_t)(l * 3 + 2);
            run_mamba(stream, W, W + OFF_LN, nullptr,
                      W + OFF_HIST + (size_t)(5 + l) * HSZ, 1, 1,
                      in_proj_w + o * 512 * 128, conv_w + o * 256 * 4, conv_b + o * 256,
                      x_proj_w + o * 40 * 256, dt_proj_w + o * 256 * 8, dt_proj_b + o * 256,
                      A_log + o * 256 * 16, D_ssm + o * 256, out_proj_w + o * 128 * 256,
                      BNq, Mq, 1);
        }
        combine_ch<<<TOKq, 128, 0, stream>>>(W, l);
    }

    // ---- Norm2D + head ----
    ln128_kernel<<<TOKq, 64, 0, stream>>>(W + OFF_HIST + 8 * HSZ, n2d_w1, n2d_b1, W + OFF_LN);
    final_ln2<<<(BMq * Dq + 255) / 256, 256, 0, stream>>>(W + OFF_LN, n2d_w2, n2d_b2, W + OFF_MIX);
    {
        dim3 gh((PREDq + 63) / 64, (BMq + 63) / 64);
        gemm_tn<<<gh, 256, 0, stream>>>(W + OFF_MIX, Nq * Dq, head_w, Nq * Dq,
                                        head_b, nullptr, 0, W + OFF_HEAD, PREDq,
                                        BMq, PREDq, Nq * Dq, 0, 0);
    }
    finalize_kernel<<<(Bq * PREDq * Mq + 255) / 256, 256, 0, stream>>>(
        W + OFF_HEAD, W + OFF_MEANS, W + OFF_STDS, out);
}

// Round 3
// 1878.097 us; speedup vs baseline: 2.3692x; 2.3692x over previous
//
#include <hip/hip_runtime.h>
#include <hip/hip_bf16.h>
#include <cstddef>

// ---- problem dims ----
#define Bq    16
#define Lq    512
#define Mq    32
#define PREDq 96
#define Pq    16
#define Sq    8
#define Dq    128
#define NSTq  16
#define DCq   4
#define NLq   4
#define Nq    63
#define DIq   256
#define DTRq  8
#define TOKq  32256   // 512*63 == 1008*32
#define BMq   512
#define BNq   1008

typedef __attribute__((ext_vector_type(8))) short short8;
typedef __attribute__((ext_vector_type(4))) float f32x4;
typedef __hip_bfloat16 bf16;

// ---- workspace layout (float offsets). total 54,578,176 floats = 218.3 MiB ----
constexpr size_t HSZ       = (size_t)TOKq * Dq;              // 4,128,768
constexpr size_t OFF_MEANS = 0;
constexpr size_t OFF_STDS  = 512;
constexpr size_t OFF_HEAD  = 1024;                           // 512*96 = 49152
constexpr size_t OFF_PART  = 50176;                          // 12 * 49152
constexpr size_t OFF_HIST  = 640000;                         // 9 * HSZ
constexpr size_t OFF_MIX   = OFF_HIST + 9 * HSZ;             // fp32 TOK*128
constexpr size_t OFF_XD    = OFF_MIX + HSZ;                  // fp32 TOK*40
constexpr size_t OFF_XZB   = OFF_XD + (size_t)TOKq * 40;     // bf16 TOK*512 (8,257,536 f)
constexpr size_t OFF_LNB   = OFF_XZB + (size_t)TOKq * 256;   // bf16 TOK*128 (2,064,384 f)
constexpr size_t OFF_WB    = OFF_LNB + (size_t)TOKq * 64;    // bf16 weights (1,038,336 f)
constexpr size_t WS_FLOATS = OFF_WB + 1038336;
// bf16-element offsets inside WB region:
constexpr size_t WBE_IN   = 0;           // 12*512*128 = 786432
constexpr size_t WBE_X    = 786432;      // 12*40*256  = 122880
constexpr size_t WBE_OUT  = 909312;      // 12*128*256 = 393216
constexpr size_t WBE_HEAD = 1302528;     // 96*8064    = 774144

__device__ __forceinline__ float silu_f(float v) { return v / (1.f + __expf(-v)); }

// ============ fp32 -> bf16 weight conversion ============
__global__ __launch_bounds__(256) void f2b_kernel(const float* __restrict__ s,
                                                  bf16* __restrict__ d, int n) {
    int i = blockIdx.x * 256 + threadIdx.x;
    if (i < n) d[i] = __float2bfloat16(s[i]);
}

// ============ stats: per (b,m) mean / unbiased std over L ============
__global__ __launch_bounds__(256) void stats_kernel(const float* __restrict__ x,
                                                    float* __restrict__ means,
                                                    float* __restrict__ stds) {
    int bm = blockIdx.x; int b = bm >> 5, m = bm & 31;
    int tid = threadIdx.x;
    float s = 0.f, ss = 0.f;
    for (int l = tid; l < Lq; l += 256) {
        float v = x[((size_t)b * Lq + l) * Mq + m];
        s += v; ss += v * v;
    }
#pragma unroll
    for (int o = 32; o >= 1; o >>= 1) { s += __shfl_xor(s, o); ss += __shfl_xor(ss, o); }
    __shared__ float sh0[4], sh1[4];
    if ((tid & 63) == 0) { sh0[tid >> 6] = s; sh1[tid >> 6] = ss; }
    __syncthreads();
    if (tid == 0) {
        float S  = sh0[0] + sh0[1] + sh0[2] + sh0[3];
        float SS = sh1[0] + sh1[1] + sh1[2] + sh1[3];
        float mean = S * (1.f / (float)Lq);
        float var  = (SS - (float)Lq * mean * mean) * (1.f / (float)(Lq - 1));
        means[bm] = mean;
        stds[bm]  = sqrtf(fmaxf(var, 0.f)) + 1e-5f;
    }
}

// ============ patch embed -> hist[0] (fp32) ============
__global__ __launch_bounds__(128) void patch_embed(const float* __restrict__ x,
                                                   const float* __restrict__ means,
                                                   const float* __restrict__ stds,
                                                   const float* __restrict__ pw,
                                                   const float* __restrict__ pb,
                                                   const float* __restrict__ pos,
                                                   float* __restrict__ h) {
    int blk = blockIdx.x;
    int bm = blk / Nq, n = blk - bm * Nq;
    int b = bm >> 5, m = bm & 31;
    int d = threadIdx.x;
    __shared__ float sx[Pq];
    if (d < Pq) {
        int l = n * Sq + d;
        sx[d] = (x[((size_t)b * Lq + l) * Mq + m] - means[bm]) / stds[bm];
    }
    __syncthreads();
    float acc = pb[d];
#pragma unroll
    for (int p = 0; p < Pq; p++) acc += sx[p] * pw[d * Pq + p];
    h[(size_t)blk * Dq + d] = acc + pos[n * Dq + d];
}

// ============ bf16 MFMA GEMM: C(M,N) = A(M,K) @ B(N,K)^T ============
// A,B bf16 row-major [row][k]. Tile 128(M) x 64(N) x 32(K), 4 waves.
// Output either bf16 (Cb) or fp32 (C) with optional resid/accum/rowmap.
// Split-K via gridDim.z: kbase = z*kstride, C += z*c_split_stride.
// MFMA layout (verified m89/m92): frag [row=lane&15][k=(lane>>4)*8+j];
// D: col(n)=lane&15, row(m)=(lane>>4)*4+reg.
__global__ __launch_bounds__(256) void gemm_bf16(
        const bf16* __restrict__ A, int lda,
        const bf16* __restrict__ Bw, int ldb,
        const float* __restrict__ resid, int ldr,
        float* __restrict__ C, bf16* __restrict__ Cb, int ldc,
        int M, int N, int Klen, int kstride, size_t c_split_stride,
        int accum, int rowmap) {
    __shared__ __align__(16) short Al[128 * 40];
    __shared__ __align__(16) short Bl[64 * 40];
    int tid = threadIdx.x;
    int wave = tid >> 6, lane = tid & 63;
    int m0 = blockIdx.y * 128, n0 = blockIdx.x * 64;
    int kbase = blockIdx.z * kstride;
    f32x4 acc[2][4];
#pragma unroll
    for (int i = 0; i < 2; i++)
#pragma unroll
        for (int j = 0; j < 4; j++) acc[i][j] = (f32x4){0.f, 0.f, 0.f, 0.f};

    int ar = tid >> 1, ah = tid & 1;          // A staging: row, 16-elem half
    int br = tid >> 2, bq2 = tid & 3;         // B staging: row, 8-elem quarter
    int mlane = lane & 15, koff = (lane >> 4) * 8;

    for (int k0 = 0; k0 < Klen; k0 += 32) {
        {   // stage A tile 128x32
            const bf16* src = A + (size_t)(m0 + ar) * lda + kbase + k0 + ah * 16;
            uint4 v0 = *(const uint4*)src;
            uint4 v1 = *(const uint4*)(src + 8);
            *(uint4*)&Al[ar * 40 + ah * 16]     = v0;
            *(uint4*)&Al[ar * 40 + ah * 16 + 8] = v1;
        }
        {   // stage B tile 64x32 (zero-pad rows >= N)
            int gn = n0 + br;
            uint4 v = {0u, 0u, 0u, 0u};
            if (gn < N) v = *(const uint4*)(Bw + (size_t)gn * ldb + kbase + k0 + bq2 * 8);
            *(uint4*)&Bl[br * 40 + bq2 * 8] = v;
        }
        __syncthreads();
        short8 a0 = *(const short8*)&Al[(wave * 32 + mlane) * 40 + koff];
        short8 a1 = *(const short8*)&Al[(wave * 32 + 16 + mlane) * 40 + koff];
#pragma unroll
        for (int ns = 0; ns < 4; ns++) {
            short8 bfr = *(const short8*)&Bl[(ns * 16 + mlane) * 40 + koff];
            acc[0][ns] = __builtin_amdgcn_mfma_f32_16x16x32_bf16(a0, bfr, acc[0][ns], 0, 0, 0);
            acc[1][ns] = __builtin_amdgcn_mfma_f32_16x16x32_bf16(a1, bfr, acc[1][ns], 0, 0, 0);
        }
        __syncthreads();
    }

    float* Cz = C + (size_t)blockIdx.z * c_split_stride;
#pragma unroll
    for (int ms = 0; ms < 2; ms++) {
#pragma unroll
        for (int ns = 0; ns < 4; ns++) {
            int n = n0 + ns * 16 + mlane;
            if (n >= N) continue;
#pragma unroll
            for (int r = 0; r < 4; r++) {
                int m = m0 + wave * 32 + ms * 16 + (lane >> 4) * 4 + r;
                int orow = m;
                if (rowmap) {                       // (b*63+n)*32+m  ->  (b*32+m)*63+n
                    int bn = m >> 5, mm = m & 31;
                    int b = bn / Nq, nn = bn - b * Nq;
                    orow = (b * Mq + mm) * Nq + nn;
                }
                float v = acc[ms][ns][r];
                if (resid) v += resid[(size_t)orow * ldr + n];
                if (Cb) {
                    Cb[(size_t)orow * ldc + n] = __float2bfloat16(v);
                } else {
                    size_t o = (size_t)orow * ldc + n;
                    if (accum) Cz[o] += v; else Cz[o] = v;
                }
            }
        }
    }
}

// ============ head split-K reduce + bias ============
__global__ __launch_bounds__(256) void head_reduce(const float* __restrict__ part,
                                                   const float* __restrict__ bias,
                                                   float* __restrict__ out) {
    int i = blockIdx.x * 256 + threadIdx.x;
    if (i >= BMq * PREDq) return;
    float s = bias[i % PREDq];
#pragma unroll
    for (int z = 0; z < 12; z++) s += part[(size_t)z * BMq * PREDq + i];
    out[i] = s;
}

// ============ in-place causal depthwise conv (DC=4) + SiLU, bf16 xz cols 0..255 ============
__global__ __launch_bounds__(256) void conv_silu(bf16* __restrict__ xz,
                                                 const float* __restrict__ cw,
                                                 const float* __restrict__ cb,
                                                 int nb, int slen, int rev) {
    int idx = blockIdx.x * 256 + threadIdx.x;
    if (idx >= nb * DIq) return;
    int row = idx >> 8, c = idx & 255;
    float w0 = cw[c * 4 + 0], w1 = cw[c * 4 + 1], w2 = cw[c * 4 + 2], w3 = cw[c * 4 + 3];
    float bv = cb[c];
    float a = 0.f, bq = 0.f, cq = 0.f;
    if (!rev) {
        for (int s = 0; s < slen; s++) {
            size_t o = ((size_t)row * slen + s) * 512 + c;
            float xc = __bfloat162float(xz[o]);
            float v = w0 * a + w1 * bq + w2 * cq + w3 * xc + bv;
            xz[o] = __float2bfloat16(silu_f(v));
            a = bq; bq = cq; cq = xc;
        }
    } else {
        for (int s = slen - 1; s >= 0; s--) {
            size_t o = ((size_t)row * slen + s) * 512 + c;
            float xc = __bfloat162float(xz[o]);
            float v = w0 * a + w1 * bq + w2 * cq + w3 * xc + bv;
            xz[o] = __float2bfloat16(silu_f(v));
            a = bq; bq = cq; cq = xc;
        }
    }
}

// ============ fused dt_proj + softplus + scan + D skip + z gate (bf16 u/z/y) ============
__global__ __launch_bounds__(256) void scan_kernel(bf16* __restrict__ xz,
                                                   const float* __restrict__ xd,
                                                   const float* __restrict__ dtw,
                                                   const float* __restrict__ dtb,
                                                   const float* __restrict__ alog,
                                                   const float* __restrict__ Dp,
                                                   int slen, int rev) {
    int row = blockIdx.x;
    int d = threadIdx.x;
    __shared__ float sh[40];
    float A[16], h[16];
#pragma unroll
    for (int j = 0; j < 16; j++) { A[j] = -__expf(alog[d * 16 + j]); h[j] = 0.f; }
    float dw[8];
#pragma unroll
    for (int r = 0; r < 8; r++) dw[r] = dtw[d * 8 + r];
    float dbv = dtb[d], Dv = Dp[d];
    for (int st = 0; st < slen; st++) {
        int s = rev ? (slen - 1 - st) : st;
        size_t t = (size_t)row * slen + s;
        __syncthreads();
        if (d < 40) sh[d] = xd[t * 40 + d];
        __syncthreads();
        float dtv = dbv;
#pragma unroll
        for (int r = 0; r < 8; r++) dtv += dw[r] * sh[r];
        dtv = fmaxf(dtv, 0.f) + __logf(1.f + __expf(-fabsf(dtv)));
        size_t o = t * 512 + d;
        float uv = __bfloat162float(xz[o]);
        float zv = __bfloat162float(xz[o + 256]);
        float du = dtv * uv;
        float y = 0.f;
#pragma unroll
        for (int j = 0; j < 16; j++) {
            h[j] = h[j] * __expf(dtv * A[j]) + du * sh[8 + j];
            y += h[j] * sh[24 + j];
        }
        xz[o] = __float2bfloat16((y + uv * Dv) * silu_f(zv));
    }
}

// ============ token mix + LN (MIX fp32, LN out bf16) ============
__global__ __launch_bounds__(64) void mix_ln_tok(float* __restrict__ W, bf16* __restrict__ lnb_out,
                                                 const float* __restrict__ alpha,
                                                 const float* __restrict__ beta,
                                                 const float* __restrict__ lnw,
                                                 const float* __restrict__ lnb, int l) {
    int t = blockIdx.x, d = threadIdx.x;
    int cnt = l + 1;
    float aw[4], bw[4];
    float amax = -1e30f, bmax = -1e30f;
    for (int i = 0; i < cnt; i++) {
        aw[i] = alpha[l * 4 + i]; bw[i] = beta[l * 4 + i];
        amax = fmaxf(amax, aw[i]); bmax = fmaxf(bmax, bw[i]);
    }
    float as = 0.f, bs = 0.f;
    for (int i = 0; i < cnt; i++) {
        aw[i] = __expf(aw[i] - amax); as += aw[i];
        bw[i] = __expf(bw[i] - bmax); bs += bw[i];
    }
    float ai = 1.f / as, bi = 1.f / bs;
    float v0 = 0.f, v1 = 0.f;
    for (int i = 0; i < cnt; i++) {
        const float* yt = W + OFF_HIST + (size_t)(i == 0 ? 0 : i) * HSZ + (size_t)t * 128;
        const float* yc = W + OFF_HIST + (size_t)(i == 0 ? 0 : 4 + i) * HSZ + (size_t)t * 128;
        float wa = aw[i] * ai, wb = bw[i] * bi;
        v0 += wa * yt[d]      + wb * yc[d];
        v1 += wa * yt[d + 64] + wb * yc[d + 64];
    }
    float* mix = W + OFF_MIX + (size_t)t * 128;
    mix[d] = v0; mix[d + 64] = v1;
    float s = v0 + v1, ss = v0 * v0 + v1 * v1;
#pragma unroll
    for (int o = 32; o >= 1; o >>= 1) { s += __shfl_xor(s, o); ss += __shfl_xor(ss, o); }
    float mean = s * (1.f / 128.f);
    float var  = ss * (1.f / 128.f) - mean * mean;
    float rstd = rsqrtf(var + 1e-5f);
    bf16* lo = lnb_out + (size_t)t * 128;
    lo[d]      = __float2bfloat16((v0 - mean) * rstd * lnw[d]      + lnb[d]);
    lo[d + 64] = __float2bfloat16((v1 - mean) * rstd * lnw[d + 64] + lnb[d + 64]);
}

// ============ channel mix + LN + transpose (LN out bf16, channel layout) ============
__global__ __launch_bounds__(64) void mix_ln_ch(float* __restrict__ W, bf16* __restrict__ lnb_out,
                                                const float* __restrict__ theta,
                                                const float* __restrict__ gamma,
                                                const float* __restrict__ lnw,
                                                const float* __restrict__ lnb, int l) {
    int t = blockIdx.x, d = threadIdx.x;
    int ct = l + 2, cg = l + 1;
    float tw[5], gw[4];
    float tmax = -1e30f, gmax = -1e30f;
    for (int i = 0; i < ct; i++) { tw[i] = theta[l * 5 + i]; tmax = fmaxf(tmax, tw[i]); }
    for (int i = 0; i < cg; i++) { gw[i] = gamma[l * 4 + i]; gmax = fmaxf(gmax, gw[i]); }
    float ts = 0.f, gs = 0.f;
    for (int i = 0; i < ct; i++) { tw[i] = __expf(tw[i] - tmax); ts += tw[i]; }
    for (int i = 0; i < cg; i++) { gw[i] = __expf(gw[i] - gmax); gs += gw[i]; }
    float ti = 1.f / ts, gi = 1.f / gs;
    float v0 = 0.f, v1 = 0.f;
    for (int i = 0; i < ct; i++) {
        const float* yt = W + OFF_HIST + (size_t)(i == 0 ? 0 : i) * HSZ + (size_t)t * 128;
        float w_ = tw[i] * ti;
        v0 += w_ * yt[d]; v1 += w_ * yt[d + 64];
    }
    for (int i = 0; i < cg; i++) {
        const float* yc = W + OFF_HIST + (size_t)(i == 0 ? 0 : 4 + i) * HSZ + (size_t)t * 128;
        float w_ = gw[i] * gi;
        v0 += w_ * yc[d]; v1 += w_ * yc[d + 64];
    }
    float* mix = W + OFF_MIX + (size_t)t * 128;
    mix[d] = v0; mix[d + 64] = v1;
    float s = v0 + v1, ss = v0 * v0 + v1 * v1;
#pragma unroll
    for (int o = 32; o >= 1; o >>= 1) { s += __shfl_xor(s, o); ss += __shfl_xor(ss, o); }
    float mean = s * (1.f / 128.f);
    float var  = ss * (1.f / 128.f) - mean * mean;
    float rstd = rsqrtf(var + 1e-5f);
    int bm = t / Nq, n = t - bm * Nq, b = bm >> 5, m = bm & 31;
    bf16* lo = lnb_out + (size_t)((b * Nq + n) * Mq + m) * 128;
    lo[d]      = __float2bfloat16((v0 - mean) * rstd * lnw[d]      + lnb[d]);
    lo[d + 64] = __float2bfloat16((v1 - mean) * rstd * lnw[d + 64] + lnb[d + 64]);
}

// ============ channel residual: hist[5+l] += MIX ============
__global__ __launch_bounds__(128) void combine_ch(float* __restrict__ W, int l) {
    size_t i = (size_t)blockIdx.x * 128 + threadIdx.x;
    W[OFF_HIST + (size_t)(5 + l) * HSZ + i] += W[OFF_MIX + i];
}

// ============ plain LN over D=128 (fp32 out) ============
__global__ __launch_bounds__(64) void ln128_kernel(const float* __restrict__ in,
                                                   const float* __restrict__ w,
                                                   const float* __restrict__ b,
                                                   float* __restrict__ out) {
    int t = blockIdx.x, d = threadIdx.x;
    float v0 = in[(size_t)t * 128 + d], v1 = in[(size_t)t * 128 + d + 64];
    float s = v0 + v1, ss = v0 * v0 + v1 * v1;
#pragma unroll
    for (int o = 32; o >= 1; o >>= 1) { s += __shfl_xor(s, o); ss += __shfl_xor(ss, o); }
    float mean = s * (1.f / 128.f);
    float var  = ss * (1.f / 128.f) - mean * mean;
    float rstd = rsqrtf(var + 1e-5f);
    out[(size_t)t * 128 + d]      = (v0 - mean) * rstd * w[d]      + b[d];
    out[(size_t)t * 128 + d + 64] = (v1 - mean) * rstd * w[d + 64] + b[d + 64];
}

// ============ LN over N=63 (per (bm,d)), bf16 out ============
__global__ __launch_bounds__(256) void final_ln2(const float* __restrict__ in,
                                                 const float* __restrict__ w2,
                                                 const float* __restrict__ b2,
                                                 bf16* __restrict__ out) {
    int idx = blockIdx.x * 256 + threadIdx.x;
    if (idx >= BMq * Dq) return;
    int bm = idx >> 7, d = idx & 127;
    float s = 0.f, ss = 0.f;
    for (int n = 0; n < Nq; n++) {
        float v = in[((size_t)bm * Nq + n) * 128 + d];
        s += v; ss += v * v;
    }
    float mean = s * (1.f / (float)Nq);
    float var  = ss * (1.f / (float)Nq) - mean * mean;
    float rstd = rsqrtf(var + 1e-5f);
    for (int n = 0; n < Nq; n++) {
        float v = in[((size_t)bm * Nq + n) * 128 + d];
        out[((size_t)bm * Nq + n) * 128 + d] = __float2bfloat16((v - mean) * rstd * w2[n] + b2[n]);
    }
}

// ============ final rescale & transpose ============
__global__ __launch_bounds__(256) void finalize_kernel(const float* __restrict__ ht,
                                                       const float* __restrict__ means,
                                                       const float* __restrict__ stds,
                                                       float* __restrict__ out) {
    int idx = blockIdx.x * 256 + threadIdx.x;
    if (idx >= Bq * PREDq * Mq) return;
    int b = idx / (PREDq * Mq);
    int r = idx - b * PREDq * Mq;
    int pr = r >> 5, m = r & 31;
    int bm = b * Mq + m;
    out[idx] = ht[(size_t)bm * PREDq + pr] * stds[bm] + means[bm];
}

// ============ host-side mamba driver ============
static void run_mamba(hipStream_t stream, float* W, const bf16* lnb_in,
                      const float* resid, float* dst, int accum, int rowmap,
                      const bf16* wb_in, const float* cw, const float* cb,
                      const bf16* wb_x, const float* dtw, const float* dtb,
                      const float* alog, const float* Dp, const bf16* wb_out,
                      int nb, int slen, int rev) {
    bf16* xz = (bf16*)(W + OFF_XZB);
    // in_proj: xz(T,512) bf16 = ln(T,128) @ inw(512,128)^T
    gemm_bf16<<<dim3(8, 252, 1), 256, 0, stream>>>(
        lnb_in, 128, wb_in, 128, nullptr, 0, nullptr, xz, 512,
        TOKq, 512, 128, 0, 0, 0, 0);
    conv_silu<<<(nb * DIq + 255) / 256, 256, 0, stream>>>(xz, cw, cb, nb, slen, rev);
    // x_proj: xdbl(T,40) fp32 = u(T,256;ld512) @ xw(40,256)^T
    gemm_bf16<<<dim3(1, 252, 1), 256, 0, stream>>>(
        xz, 512, wb_x, 256, nullptr, 0, W + OFF_XD, nullptr, 40,
        TOKq, 40, 256, 0, 0, 0, 0);
    scan_kernel<<<nb, 256, 0, stream>>>(xz, W + OFF_XD, dtw, dtb, alog, Dp, slen, rev);
    // out_proj: dst(T,128) fp32 (+resid)(accum)(rowmap) = y(T,256;ld512) @ ow(128,256)^T
    gemm_bf16<<<dim3(2, 252, 1), 256, 0, stream>>>(
        xz, 512, wb_out, 256, resid, 128, dst, nullptr, 128,
        TOKq, 128, 256, 0, 0, accum, rowmap);
}

extern "C" void kernel_launch(void* const* d_in, const int* in_sizes, int n_in,
                              void* d_out, int out_size, void* d_ws, size_t ws_size,
                              hipStream_t stream) {
    if (ws_size < WS_FLOATS * sizeof(float)) return;

    const float* x          = (const float*)d_in[0];
    const float* patch_w    = (const float*)d_in[1];
    const float* patch_b    = (const float*)d_in[2];
    const float* pos_embed  = (const float*)d_in[3];
    const float* alpha      = (const float*)d_in[4];
    const float* beta       = (const float*)d_in[5];
    const float* theta      = (const float*)d_in[6];
    const float* gamma      = (const float*)d_in[7];
    const float* tok_norm_w = (const float*)d_in[8];
    const float* tok_norm_b = (const float*)d_in[9];
    const float* ch_norm_w  = (const float*)d_in[10];
    const float* ch_norm_b  = (const float*)d_in[11];
    const float* in_proj_w  = (const float*)d_in[12];
    const float* conv_w     = (const float*)d_in[13];
    const float* conv_b     = (const float*)d_in[14];
    const float* x_proj_w   = (const float*)d_in[15];
    const float* dt_proj_w  = (const float*)d_in[16];
    const float* dt_proj_b  = (const float*)d_in[17];
    const float* A_log      = (const float*)d_in[18];
    const float* D_ssm      = (const float*)d_in[19];
    const float* out_proj_w = (const float*)d_in[20];
    const float* n2d_w1     = (const float*)d_in[21];
    const float* n2d_b1     = (const float*)d_in[22];
    const float* n2d_w2     = (const float*)d_in[23];
    const float* n2d_b2     = (const float*)d_in[24];
    const float* head_w     = (const float*)d_in[25];
    const float* head_b     = (const float*)d_in[26];

    float* W   = (float*)d_ws;
    float* out = (float*)d_out;
    bf16* WB   = (bf16*)(W + OFF_WB);
    bf16* LNB  = (bf16*)(W + OFF_LNB);

    // weight conversions (once per launch; re-done every call, graph-safe)
    f2b_kernel<<<(786432 + 255) / 256, 256, 0, stream>>>(in_proj_w,  WB + WBE_IN,   786432);
    f2b_kernel<<<(122880 + 255) / 256, 256, 0, stream>>>(x_proj_w,   WB + WBE_X,    122880);
    f2b_kernel<<<(393216 + 255) / 256, 256, 0, stream>>>(out_proj_w, WB + WBE_OUT,  393216);
    f2b_kernel<<<(774144 + 255) / 256, 256, 0, stream>>>(head_w,     WB + WBE_HEAD, 774144);

    stats_kernel<<<BMq, 256, 0, stream>>>(x, W + OFF_MEANS, W + OFF_STDS);
    patch_embed<<<TOKq, 128, 0, stream>>>(x, W + OFF_MEANS, W + OFF_STDS,
                                          patch_w, patch_b, pos_embed, W + OFF_HIST);

    for (int l = 0; l < NLq; l++) {
        // ---- token mamba ----
        mix_ln_tok<<<TOKq, 64, 0, stream>>>(W, LNB, alpha, beta,
                                            tok_norm_w + l * Dq, tok_norm_b + l * Dq, l);
        {
            size_t o = (size_t)(l * 3 + 0);
            run_mamba(stream, W, LNB, W + OFF_MIX,
                      W + OFF_HIST + (size_t)(1 + l) * HSZ, 0, 0,
                      WB + WBE_IN + o * 512 * 128, conv_w + o * 256 * 4, conv_b + o * 256,
                      WB + WBE_X + o * 40 * 256, dt_proj_w + o * 256 * 8, dt_proj_b + o * 256,
                      A_log + o * 256 * 16, D_ssm + o * 256, WB + WBE_OUT + o * 128 * 256,
                      BMq, Nq, 0);
        }
        // ---- channel mamba (bidirectional) -> hist[5+l] ----
        mix_ln_ch<<<TOKq, 64, 0, stream>>>(W, LNB, theta, gamma,
                                           ch_norm_w + l * Dq, ch_norm_b + l * Dq, l);
        {
            size_t o = (size_t)(l * 3 + 1);
            run_mamba(stream, W, LNB, nullptr,
                      W + OFF_HIST + (size_t)(5 + l) * HSZ, 0, 1,
                      WB + WBE_IN + o * 512 * 128, conv_w + o * 256 * 4, conv_b + o * 256,
                      WB + WBE_X + o * 40 * 256, dt_proj_w + o * 256 * 8, dt_proj_b + o * 256,
                      A_log + o * 256 * 16, D_ssm + o * 256, WB + WBE_OUT + o * 128 * 256,
                      BNq, Mq, 0);
        }
        {
            size_t o = (size_t)(l * 3 + 2);
            run_mamba(stream, W, LNB, nullptr,
                      W + OFF_HIST + (size_t)(5 + l) * HSZ, 1, 1,
                      WB + WBE_IN + o * 512 * 128, conv_w + o * 256 * 4, conv_b + o * 256,
                      WB + WBE_X + o * 40 * 256, dt_proj_w + o * 256 * 8, dt_proj_b + o * 256,
                      A_log + o * 256 * 16, D_ssm + o * 256, WB + WBE_OUT + o * 128 * 256,
                      BNq, Mq, 1);
        }
        combine_ch<<<TOKq, 128, 0, stream>>>(W, l);
    }

    // ---- Norm2D + head ----
    ln128_kernel<<<TOKq, 64, 0, stream>>>(W + OFF_HIST + 8 * HSZ, n2d_w1, n2d_b1, W + OFF_MIX);
    final_ln2<<<(BMq * Dq + 255) / 256, 256, 0, stream>>>(W + OFF_MIX, n2d_w2, n2d_b2, LNB);
    // head: (512,96,K=8064) split-K 12 x 672 -> partials -> reduce
    gemm_bf16<<<dim3(2, 4, 12), 256, 0, stream>>>(
        LNB, Nq * Dq, WB + WBE_HEAD, Nq * Dq, nullptr, 0,
        W + OFF_PART, nullptr, PREDq,
        BMq, PREDq, 672, 672, (size_t)BMq * PREDq, 0, 0);
    head_reduce<<<(BMq * PREDq + 255) / 256, 256, 0, stream>>>(
        W + OFF_PART, head_b, W + OFF_HEAD);
    finalize_kernel<<<(Bq * PREDq * Mq + 255) / 256, 256, 0, stream>>>(
        W + OFF_HEAD, W + OFF_MEANS, W + OFF_STDS, out);
}

// Round 4
// 1795.450 us; speedup vs baseline: 2.4782x; 1.0460x over previous
//
#include <hip/hip_runtime.h>
#include <hip/hip_bf16.h>
#include <cstddef>

// ---- problem dims ----
#define Bq    16
#define Lq    512
#define Mq    32
#define PREDq 96
#define Pq    16
#define Sq    8
#define Dq    128
#define NSTq  16
#define DCq   4
#define NLq   4
#define Nq    63
#define DIq   256
#define DTRq  8
#define TOKq  32256   // 512*63 == 1008*32
#define BMq   512
#define BNq   1008

typedef __attribute__((ext_vector_type(8))) short short8;
typedef __attribute__((ext_vector_type(4))) float f32x4;
typedef __hip_bfloat16 bf16;

// ---- workspace layout (float offsets). total 54,578,176 floats = 218.3 MiB ----
constexpr size_t HSZ       = (size_t)TOKq * Dq;              // 4,128,768
constexpr size_t OFF_MEANS = 0;
constexpr size_t OFF_STDS  = 512;
constexpr size_t OFF_HEAD  = 1024;                           // 512*96 = 49152
constexpr size_t OFF_PART  = 50176;                          // 12 * 49152
constexpr size_t OFF_HIST  = 640000;                         // 9 * HSZ
constexpr size_t OFF_MIX   = OFF_HIST + 9 * HSZ;             // fp32 TOK*128
constexpr size_t OFF_XD    = OFF_MIX + HSZ;                  // fp32 TOK*40
constexpr size_t OFF_XZB   = OFF_XD + (size_t)TOKq * 40;     // bf16 TOK*512 (8,257,536 f)
constexpr size_t OFF_LNB   = OFF_XZB + (size_t)TOKq * 256;   // bf16 TOK*128 (2,064,384 f)
constexpr size_t OFF_WB    = OFF_LNB + (size_t)TOKq * 64;    // bf16 weights (1,038,336 f)
constexpr size_t WS_FLOATS = OFF_WB + 1038336;
// bf16-element offsets inside WB region:
constexpr size_t WBE_IN   = 0;           // 12*512*128 = 786432
constexpr size_t WBE_X    = 786432;      // 12*40*256  = 122880
constexpr size_t WBE_OUT  = 909312;      // 12*128*256 = 393216
constexpr size_t WBE_HEAD = 1302528;     // 96*8064    = 774144

__device__ __forceinline__ float silu_f(float v) { return v / (1.f + __expf(-v)); }

// ============ fp32 -> bf16 weight conversion ============
__global__ __launch_bounds__(256) void f2b_kernel(const float* __restrict__ s,
                                                  bf16* __restrict__ d, int n) {
    int i = blockIdx.x * 256 + threadIdx.x;
    if (i < n) d[i] = __float2bfloat16(s[i]);
}

// ============ stats: per (b,m) mean / unbiased std over L ============
__global__ __launch_bounds__(256) void stats_kernel(const float* __restrict__ x,
                                                    float* __restrict__ means,
                                                    float* __restrict__ stds) {
    int bm = blockIdx.x; int b = bm >> 5, m = bm & 31;
    int tid = threadIdx.x;
    float s = 0.f, ss = 0.f;
    for (int l = tid; l < Lq; l += 256) {
        float v = x[((size_t)b * Lq + l) * Mq + m];
        s += v; ss += v * v;
    }
#pragma unroll
    for (int o = 32; o >= 1; o >>= 1) { s += __shfl_xor(s, o); ss += __shfl_xor(ss, o); }
    __shared__ float sh0[4], sh1[4];
    if ((tid & 63) == 0) { sh0[tid >> 6] = s; sh1[tid >> 6] = ss; }
    __syncthreads();
    if (tid == 0) {
        float S  = sh0[0] + sh0[1] + sh0[2] + sh0[3];
        float SS = sh1[0] + sh1[1] + sh1[2] + sh1[3];
        float mean = S * (1.f / (float)Lq);
        float var  = (SS - (float)Lq * mean * mean) * (1.f / (float)(Lq - 1));
        means[bm] = mean;
        stds[bm]  = sqrtf(fmaxf(var, 0.f)) + 1e-5f;
    }
}

// ============ patch embed -> hist[0] (fp32) ============
__global__ __launch_bounds__(128) void patch_embed(const float* __restrict__ x,
                                                   const float* __restrict__ means,
                                                   const float* __restrict__ stds,
                                                   const float* __restrict__ pw,
                                                   const float* __restrict__ pb,
                                                   const float* __restrict__ pos,
                                                   float* __restrict__ h) {
    int blk = blockIdx.x;
    int bm = blk / Nq, n = blk - bm * Nq;
    int b = bm >> 5, m = bm & 31;
    int d = threadIdx.x;
    __shared__ float sx[Pq];
    if (d < Pq) {
        int l = n * Sq + d;
        sx[d] = (x[((size_t)b * Lq + l) * Mq + m] - means[bm]) / stds[bm];
    }
    __syncthreads();
    float acc = pb[d];
#pragma unroll
    for (int p = 0; p < Pq; p++) acc += sx[p] * pw[d * Pq + p];
    h[(size_t)blk * Dq + d] = acc + pos[n * Dq + d];
}

// ============ bf16 MFMA GEMM: C(M,N) = A(M,K) @ B(N,K)^T ============
// Tile 128(M) x 64(N) x 32(K), 4 waves. Split-K via gridDim.z.
__global__ __launch_bounds__(256) void gemm_bf16(
        const bf16* __restrict__ A, int lda,
        const bf16* __restrict__ Bw, int ldb,
        const float* __restrict__ resid, int ldr,
        float* __restrict__ C, bf16* __restrict__ Cb, int ldc,
        int M, int N, int Klen, int kstride, size_t c_split_stride,
        int accum, int rowmap) {
    __shared__ __align__(16) short Al[128 * 40];
    __shared__ __align__(16) short Bl[64 * 40];
    int tid = threadIdx.x;
    int wave = tid >> 6, lane = tid & 63;
    int m0 = blockIdx.y * 128, n0 = blockIdx.x * 64;
    int kbase = blockIdx.z * kstride;
    f32x4 acc[2][4];
#pragma unroll
    for (int i = 0; i < 2; i++)
#pragma unroll
        for (int j = 0; j < 4; j++) acc[i][j] = (f32x4){0.f, 0.f, 0.f, 0.f};

    int ar = tid >> 1, ah = tid & 1;
    int br = tid >> 2, bq2 = tid & 3;
    int mlane = lane & 15, koff = (lane >> 4) * 8;

    for (int k0 = 0; k0 < Klen; k0 += 32) {
        {
            const bf16* src = A + (size_t)(m0 + ar) * lda + kbase + k0 + ah * 16;
            uint4 v0 = *(const uint4*)src;
            uint4 v1 = *(const uint4*)(src + 8);
            *(uint4*)&Al[ar * 40 + ah * 16]     = v0;
            *(uint4*)&Al[ar * 40 + ah * 16 + 8] = v1;
        }
        {
            int gn = n0 + br;
            uint4 v = {0u, 0u, 0u, 0u};
            if (gn < N) v = *(const uint4*)(Bw + (size_t)gn * ldb + kbase + k0 + bq2 * 8);
            *(uint4*)&Bl[br * 40 + bq2 * 8] = v;
        }
        __syncthreads();
        short8 a0 = *(const short8*)&Al[(wave * 32 + mlane) * 40 + koff];
        short8 a1 = *(const short8*)&Al[(wave * 32 + 16 + mlane) * 40 + koff];
#pragma unroll
        for (int ns = 0; ns < 4; ns++) {
            short8 bfr = *(const short8*)&Bl[(ns * 16 + mlane) * 40 + koff];
            acc[0][ns] = __builtin_amdgcn_mfma_f32_16x16x32_bf16(a0, bfr, acc[0][ns], 0, 0, 0);
            acc[1][ns] = __builtin_amdgcn_mfma_f32_16x16x32_bf16(a1, bfr, acc[1][ns], 0, 0, 0);
        }
        __syncthreads();
    }

    float* Cz = C + (size_t)blockIdx.z * c_split_stride;
#pragma unroll
    for (int ms = 0; ms < 2; ms++) {
#pragma unroll
        for (int ns = 0; ns < 4; ns++) {
            int n = n0 + ns * 16 + mlane;
            if (n >= N) continue;
#pragma unroll
            for (int r = 0; r < 4; r++) {
                int m = m0 + wave * 32 + ms * 16 + (lane >> 4) * 4 + r;
                int orow = m;
                if (rowmap) {                       // (b*63+n)*32+m  ->  (b*32+m)*63+n
                    int bn = m >> 5, mm = m & 31;
                    int b = bn / Nq, nn = bn - b * Nq;
                    orow = (b * Mq + mm) * Nq + nn;
                }
                float v = acc[ms][ns][r];
                if (resid) v += resid[(size_t)orow * ldr + n];
                if (Cb) {
                    Cb[(size_t)orow * ldc + n] = __float2bfloat16(v);
                } else {
                    size_t o = (size_t)orow * ldc + n;
                    if (accum) Cz[o] += v; else Cz[o] = v;
                }
            }
        }
    }
}

// ============ head split-K reduce + bias ============
__global__ __launch_bounds__(256) void head_reduce(const float* __restrict__ part,
                                                   const float* __restrict__ bias,
                                                   float* __restrict__ out) {
    int i = blockIdx.x * 256 + threadIdx.x;
    if (i >= BMq * PREDq) return;
    float s = bias[i % PREDq];
#pragma unroll
    for (int z = 0; z < 12; z++) s += part[(size_t)z * BMq * PREDq + i];
    out[i] = s;
}

// ============ in-place causal depthwise conv (DC=4) + SiLU, bf16 xz cols 0..255 ============
__global__ __launch_bounds__(256) void conv_silu(bf16* __restrict__ xz,
                                                 const float* __restrict__ cw,
                                                 const float* __restrict__ cb,
                                                 int nb, int slen, int rev) {
    int idx = blockIdx.x * 256 + threadIdx.x;
    if (idx >= nb * DIq) return;
    int row = idx >> 8, c = idx & 255;
    float w0 = cw[c * 4 + 0], w1 = cw[c * 4 + 1], w2 = cw[c * 4 + 2], w3 = cw[c * 4 + 3];
    float bv = cb[c];
    float a = 0.f, bq = 0.f, cq = 0.f;
    if (!rev) {
        for (int s = 0; s < slen; s++) {
            size_t o = ((size_t)row * slen + s) * 512 + c;
            float xc = __bfloat162float(xz[o]);
            float v = w0 * a + w1 * bq + w2 * cq + w3 * xc + bv;
            xz[o] = __float2bfloat16(silu_f(v));
            a = bq; bq = cq; cq = xc;
        }
    } else {
        for (int s = slen - 1; s >= 0; s--) {
            size_t o = ((size_t)row * slen + s) * 512 + c;
            float xc = __bfloat162float(xz[o]);
            float v = w0 * a + w1 * bq + w2 * cq + w3 * xc + bv;
            xz[o] = __float2bfloat16(silu_f(v));
            a = bq; bq = cq; cq = xc;
        }
    }
}

// ============ fused dt_proj + softplus + scan + D skip + z gate ============
// v2: whole-row xd staged in LDS once (no per-step barriers), b128 LDS reads,
// software-pipelined u/z global loads.
__global__ __launch_bounds__(256) void scan_kernel(bf16* __restrict__ xz,
                                                   const float* __restrict__ xd,
                                                   const float* __restrict__ dtw,
                                                   const float* __restrict__ dtb,
                                                   const float* __restrict__ alog,
                                                   const float* __restrict__ Dp,
                                                   int slen, int rev) {
    __shared__ __align__(16) float sxd[63 * 40];
    int row = blockIdx.x;
    int d = threadIdx.x;
    const float* src = xd + (size_t)row * slen * 40;
    for (int i = d; i < slen * 40; i += 256) sxd[i] = src[i];
    __syncthreads();

    float A2[16], h[16];
#pragma unroll
    for (int j = 0; j < 16; j++) { A2[j] = -__expf(alog[d * 16 + j]); h[j] = 0.f; }
    float dw[8];
#pragma unroll
    for (int r = 0; r < 8; r++) dw[r] = dtw[d * 8 + r];
    float dbv = dtb[d], Dv = Dp[d];

    int s = rev ? (slen - 1) : 0;
    int dstep = rev ? -1 : 1;
    long ostride = (long)dstep * 512;
    size_t o = ((size_t)row * slen + s) * 512 + d;

    float uv = __bfloat162float(xz[o]);
    float zv = __bfloat162float(xz[o + 256]);

    for (int st = 0; st < slen; st++) {
        float un = 0.f, zn = 0.f;
        if (st + 1 < slen) {                       // prefetch next step's u/z
            size_t on = o + ostride;
            un = __bfloat162float(xz[on]);
            zn = __bfloat162float(xz[on + 256]);
        }
        const float4* q = (const float4*)(sxd + s * 40);
        float4 q0 = q[0], q1 = q[1];
        float dtv = dbv + dw[0]*q0.x + dw[1]*q0.y + dw[2]*q0.z + dw[3]*q0.w
                        + dw[4]*q1.x + dw[5]*q1.y + dw[6]*q1.z + dw[7]*q1.w;
        dtv = fmaxf(dtv, 0.f) + __logf(1.f + __expf(-fabsf(dtv)));   // softplus
        float Bv[16], Cv[16];
        *(float4*)&Bv[0]  = q[2]; *(float4*)&Bv[4]  = q[3];
        *(float4*)&Bv[8]  = q[4]; *(float4*)&Bv[12] = q[5];
        *(float4*)&Cv[0]  = q[6]; *(float4*)&Cv[4]  = q[7];
        *(float4*)&Cv[8]  = q[8]; *(float4*)&Cv[12] = q[9];
        float du = dtv * uv;
        float y = 0.f;
#pragma unroll
        for (int j = 0; j < 16; j++) {
            h[j] = h[j] * __expf(dtv * A2[j]) + du * Bv[j];
            y += h[j] * Cv[j];
        }
        xz[o] = __float2bfloat16((y + uv * Dv) * silu_f(zv));
        uv = un; zv = zn;
        o += ostride; s += dstep;
    }
}

// ============ token mix + LN (MIX fp32, LN out bf16) ============
__global__ __launch_bounds__(64) void mix_ln_tok(float* __restrict__ W, bf16* __restrict__ lnb_out,
                                                 const float* __restrict__ alpha,
                                                 const float* __restrict__ beta,
                                                 const float* __restrict__ lnw,
                                                 const float* __restrict__ lnb, int l) {
    int t = blockIdx.x, d = threadIdx.x;
    int cnt = l + 1;
    float aw[4], bw[4];
    float amax = -1e30f, bmax = -1e30f;
    for (int i = 0; i < cnt; i++) {
        aw[i] = alpha[l * 4 + i]; bw[i] = beta[l * 4 + i];
        amax = fmaxf(amax, aw[i]); bmax = fmaxf(bmax, bw[i]);
    }
    float as = 0.f, bs = 0.f;
    for (int i = 0; i < cnt; i++) {
        aw[i] = __expf(aw[i] - amax); as += aw[i];
        bw[i] = __expf(bw[i] - bmax); bs += bw[i];
    }
    float ai = 1.f / as, bi = 1.f / bs;
    float v0 = 0.f, v1 = 0.f;
    for (int i = 0; i < cnt; i++) {
        const float* yt = W + OFF_HIST + (size_t)(i == 0 ? 0 : i) * HSZ + (size_t)t * 128;
        const float* yc = W + OFF_HIST + (size_t)(i == 0 ? 0 : 4 + i) * HSZ + (size_t)t * 128;
        float wa = aw[i] * ai, wb = bw[i] * bi;
        v0 += wa * yt[d]      + wb * yc[d];
        v1 += wa * yt[d + 64] + wb * yc[d + 64];
    }
    float* mix = W + OFF_MIX + (size_t)t * 128;
    mix[d] = v0; mix[d + 64] = v1;
    float s = v0 + v1, ss = v0 * v0 + v1 * v1;
#pragma unroll
    for (int o = 32; o >= 1; o >>= 1) { s += __shfl_xor(s, o); ss += __shfl_xor(ss, o); }
    float mean = s * (1.f / 128.f);
    float var  = ss * (1.f / 128.f) - mean * mean;
    float rstd = rsqrtf(var + 1e-5f);
    bf16* lo = lnb_out + (size_t)t * 128;
    lo[d]      = __float2bfloat16((v0 - mean) * rstd * lnw[d]      + lnb[d]);
    lo[d + 64] = __float2bfloat16((v1 - mean) * rstd * lnw[d + 64] + lnb[d + 64]);
}

// ============ channel mix + LN + transpose (LN out bf16, channel layout) ============
__global__ __launch_bounds__(64) void mix_ln_ch(float* __restrict__ W, bf16* __restrict__ lnb_out,
                                                const float* __restrict__ theta,
                                                const float* __restrict__ gamma,
                                                const float* __restrict__ lnw,
                                                const float* __restrict__ lnb, int l) {
    int t = blockIdx.x, d = threadIdx.x;
    int ct = l + 2, cg = l + 1;
    float tw[5], gw[4];
    float tmax = -1e30f, gmax = -1e30f;
    for (int i = 0; i < ct; i++) { tw[i] = theta[l * 5 + i]; tmax = fmaxf(tmax, tw[i]); }
    for (int i = 0; i < cg; i++) { gw[i] = gamma[l * 4 + i]; gmax = fmaxf(gmax, gw[i]); }
    float ts = 0.f, gs = 0.f;
    for (int i = 0; i < ct; i++) { tw[i] = __expf(tw[i] - tmax); ts += tw[i]; }
    for (int i = 0; i < cg; i++) { gw[i] = __expf(gw[i] - gmax); gs += gw[i]; }
    float ti = 1.f / ts, gi = 1.f / gs;
    float v0 = 0.f, v1 = 0.f;
    for (int i = 0; i < ct; i++) {
        const float* yt = W + OFF_HIST + (size_t)(i == 0 ? 0 : i) * HSZ + (size_t)t * 128;
        float w_ = tw[i] * ti;
        v0 += w_ * yt[d]; v1 += w_ * yt[d + 64];
    }
    for (int i = 0; i < cg; i++) {
        const float* yc = W + OFF_HIST + (size_t)(i == 0 ? 0 : 4 + i) * HSZ + (size_t)t * 128;
        float w_ = gw[i] * gi;
        v0 += w_ * yc[d]; v1 += w_ * yc[d + 64];
    }
    float* mix = W + OFF_MIX + (size_t)t * 128;
    mix[d] = v0; mix[d + 64] = v1;
    float s = v0 + v1, ss = v0 * v0 + v1 * v1;
#pragma unroll
    for (int o = 32; o >= 1; o >>= 1) { s += __shfl_xor(s, o); ss += __shfl_xor(ss, o); }
    float mean = s * (1.f / 128.f);
    float var  = ss * (1.f / 128.f) - mean * mean;
    float rstd = rsqrtf(var + 1e-5f);
    int bm = t / Nq, n = t - bm * Nq, b = bm >> 5, m = bm & 31;
    bf16* lo = lnb_out + (size_t)((b * Nq + n) * Mq + m) * 128;
    lo[d]      = __float2bfloat16((v0 - mean) * rstd * lnw[d]      + lnb[d]);
    lo[d + 64] = __float2bfloat16((v1 - mean) * rstd * lnw[d + 64] + lnb[d + 64]);
}

// ============ channel residual: hist[5+l] += MIX ============
__global__ __launch_bounds__(128) void combine_ch(float* __restrict__ W, int l) {
    size_t i = (size_t)blockIdx.x * 128 + threadIdx.x;
    W[OFF_HIST + (size_t)(5 + l) * HSZ + i] += W[OFF_MIX + i];
}

// ============ plain LN over D=128 (fp32 out) ============
__global__ __launch_bounds__(64) void ln128_kernel(const float* __restrict__ in,
                                                   const float* __restrict__ w,
                                                   const float* __restrict__ b,
                                                   float* __restrict__ out) {
    int t = blockIdx.x, d = threadIdx.x;
    float v0 = in[(size_t)t * 128 + d], v1 = in[(size_t)t * 128 + d + 64];
    float s = v0 + v1, ss = v0 * v0 + v1 * v1;
#pragma unroll
    for (int o = 32; o >= 1; o >>= 1) { s += __shfl_xor(s, o); ss += __shfl_xor(ss, o); }
    float mean = s * (1.f / 128.f);
    float var  = ss * (1.f / 128.f) - mean * mean;
    float rstd = rsqrtf(var + 1e-5f);
    out[(size_t)t * 128 + d]      = (v0 - mean) * rstd * w[d]      + b[d];
    out[(size_t)t * 128 + d + 64] = (v1 - mean) * rstd * w[d + 64] + b[d + 64];
}

// ============ LN over N=63 (per (bm,d)), bf16 out ============
__global__ __launch_bounds__(256) void final_ln2(const float* __restrict__ in,
                                                 const float* __restrict__ w2,
                                                 const float* __restrict__ b2,
                                                 bf16* __restrict__ out) {
    int idx = blockIdx.x * 256 + threadIdx.x;
    if (idx >= BMq * Dq) return;
    int bm = idx >> 7, d = idx & 127;
    float s = 0.f, ss = 0.f;
    for (int n = 0; n < Nq; n++) {
        float v = in[((size_t)bm * Nq + n) * 128 + d];
        s += v; ss += v * v;
    }
    float mean = s * (1.f / (float)Nq);
    float var  = ss * (1.f / (float)Nq) - mean * mean;
    float rstd = rsqrtf(var + 1e-5f);
    for (int n = 0; n < Nq; n++) {
        float v = in[((size_t)bm * Nq + n) * 128 + d];
        out[((size_t)bm * Nq + n) * 128 + d] = __float2bfloat16((v - mean) * rstd * w2[n] + b2[n]);
    }
}

// ============ final rescale & transpose ============
__global__ __launch_bounds__(256) void finalize_kernel(const float* __restrict__ ht,
                                                       const float* __restrict__ means,
                                                       const float* __restrict__ stds,
                                                       float* __restrict__ out) {
    int idx = blockIdx.x * 256 + threadIdx.x;
    if (idx >= Bq * PREDq * Mq) return;
    int b = idx / (PREDq * Mq);
    int r = idx - b * PREDq * Mq;
    int pr = r >> 5, m = r & 31;
    int bm = b * Mq + m;
    out[idx] = ht[(size_t)bm * PREDq + pr] * stds[bm] + means[bm];
}

// ============ host-side mamba driver ============
static void run_mamba(hipStream_t stream, float* W, const bf16* lnb_in,
                      const float* resid, float* dst, int accum, int rowmap,
                      const bf16* wb_in, const float* cw, const float* cb,
                      const bf16* wb_x, const float* dtw, const float* dtb,
                      const float* alog, const float* Dp, const bf16* wb_out,
                      int nb, int slen, int rev) {
    bf16* xz = (bf16*)(W + OFF_XZB);
    gemm_bf16<<<dim3(8, 252, 1), 256, 0, stream>>>(
        lnb_in, 128, wb_in, 128, nullptr, 0, nullptr, xz, 512,
        TOKq, 512, 128, 0, 0, 0, 0);
    conv_silu<<<(nb * DIq + 255) / 256, 256, 0, stream>>>(xz, cw, cb, nb, slen, rev);
    gemm_bf16<<<dim3(1, 252, 1), 256, 0, stream>>>(
        xz, 512, wb_x, 256, nullptr, 0, W + OFF_XD, nullptr, 40,
        TOKq, 40, 256, 0, 0, 0, 0);
    scan_kernel<<<nb, 256, 0, stream>>>(xz, W + OFF_XD, dtw, dtb, alog, Dp, slen, rev);
    gemm_bf16<<<dim3(2, 252, 1), 256, 0, stream>>>(
        xz, 512, wb_out, 256, resid, 128, dst, nullptr, 128,
        TOKq, 128, 256, 0, 0, accum, rowmap);
}

extern "C" void kernel_launch(void* const* d_in, const int* in_sizes, int n_in,
                              void* d_out, int out_size, void* d_ws, size_t ws_size,
                              hipStream_t stream) {
    if (ws_size < WS_FLOATS * sizeof(float)) return;

    const float* x          = (const float*)d_in[0];
    const float* patch_w    = (const float*)d_in[1];
    const float* patch_b    = (const float*)d_in[2];
    const float* pos_embed  = (const float*)d_in[3];
    const float* alpha      = (const float*)d_in[4];
    const float* beta       = (const float*)d_in[5];
    const float* theta      = (const float*)d_in[6];
    const float* gamma      = (const float*)d_in[7];
    const float* tok_norm_w = (const float*)d_in[8];
    const float* tok_norm_b = (const float*)d_in[9];
    const float* ch_norm_w  = (const float*)d_in[10];
    const float* ch_norm_b  = (const float*)d_in[11];
    const float* in_proj_w  = (const float*)d_in[12];
    const float* conv_w     = (const float*)d_in[13];
    const float* conv_b     = (const float*)d_in[14];
    const float* x_proj_w   = (const float*)d_in[15];
    const float* dt_proj_w  = (const float*)d_in[16];
    const float* dt_proj_b  = (const float*)d_in[17];
    const float* A_log      = (const float*)d_in[18];
    const float* D_ssm      = (const float*)d_in[19];
    const float* out_proj_w = (const float*)d_in[20];
    const float* n2d_w1     = (const float*)d_in[21];
    const float* n2d_b1     = (const float*)d_in[22];
    const float* n2d_w2     = (const float*)d_in[23];
    const float* n2d_b2     = (const float*)d_in[24];
    const float* head_w     = (const float*)d_in[25];
    const float* head_b     = (const float*)d_in[26];

    float* W   = (float*)d_ws;
    float* out = (float*)d_out;
    bf16* WB   = (bf16*)(W + OFF_WB);
    bf16* LNB  = (bf16*)(W + OFF_LNB);

    f2b_kernel<<<(786432 + 255) / 256, 256, 0, stream>>>(in_proj_w,  WB + WBE_IN,   786432);
    f2b_kernel<<<(122880 + 255) / 256, 256, 0, stream>>>(x_proj_w,   WB + WBE_X,    122880);
    f2b_kernel<<<(393216 + 255) / 256, 256, 0, stream>>>(out_proj_w, WB + WBE_OUT,  393216);
    f2b_kernel<<<(774144 + 255) / 256, 256, 0, stream>>>(head_w,     WB + WBE_HEAD, 774144);

    stats_kernel<<<BMq, 256, 0, stream>>>(x, W + OFF_MEANS, W + OFF_STDS);
    patch_embed<<<TOKq, 128, 0, stream>>>(x, W + OFF_MEANS, W + OFF_STDS,
                                          patch_w, patch_b, pos_embed, W + OFF_HIST);

    for (int l = 0; l < NLq; l++) {
        // ---- token mamba ----
        mix_ln_tok<<<TOKq, 64, 0, stream>>>(W, LNB, alpha, beta,
                                            tok_norm_w + l * Dq, tok_norm_b + l * Dq, l);
        {
            size_t o = (size_t)(l * 3 + 0);
            run_mamba(stream, W, LNB, W + OFF_MIX,
                      W + OFF_HIST + (size_t)(1 + l) * HSZ, 0, 0,
                      WB + WBE_IN + o * 512 * 128, conv_w + o * 256 * 4, conv_b + o * 256,
                      WB + WBE_X + o * 40 * 256, dt_proj_w + o * 256 * 8, dt_proj_b + o * 256,
                      A_log + o * 256 * 16, D_ssm + o * 256, WB + WBE_OUT + o * 128 * 256,
                      BMq, Nq, 0);
        }
        // ---- channel mamba (bidirectional) -> hist[5+l] ----
        mix_ln_ch<<<TOKq, 64, 0, stream>>>(W, LNB, theta, gamma,
                                           ch_norm_w + l * Dq, ch_norm_b + l * Dq, l);
        {
            size_t o = (size_t)(l * 3 + 1);
            run_mamba(stream, W, LNB, nullptr,
                      W + OFF_HIST + (size_t)(5 + l) * HSZ, 0, 1,
                      WB + WBE_IN + o * 512 * 128, conv_w + o * 256 * 4, conv_b + o * 256,
                      WB + WBE_X + o * 40 * 256, dt_proj_w + o * 256 * 8, dt_proj_b + o * 256,
                      A_log + o * 256 * 16, D_ssm + o * 256, WB + WBE_OUT + o * 128 * 256,
                      BNq, Mq, 0);
        }
        {
            size_t o = (size_t)(l * 3 + 2);
            run_mamba(stream, W, LNB, nullptr,
                      W + OFF_HIST + (size_t)(5 + l) * HSZ, 1, 1,
                      WB + WBE_IN + o * 512 * 128, conv_w + o * 256 * 4, conv_b + o * 256,
                      WB + WBE_X + o * 40 * 256, dt_proj_w + o * 256 * 8, dt_proj_b + o * 256,
                      A_log + o * 256 * 16, D_ssm + o * 256, WB + WBE_OUT + o * 128 * 256,
                      BNq, Mq, 1);
        }
        combine_ch<<<TOKq, 128, 0, stream>>>(W, l);
    }

    // ---- Norm2D + head ----
    ln128_kernel<<<TOKq, 64, 0, stream>>>(W + OFF_HIST + 8 * HSZ, n2d_w1, n2d_b1, W + OFF_MIX);
    final_ln2<<<(BMq * Dq + 255) / 256, 256, 0, stream>>>(W + OFF_MIX, n2d_w2, n2d_b2, LNB);
    gemm_bf16<<<dim3(2, 4, 12), 256, 0, stream>>>(
        LNB, Nq * Dq, WB + WBE_HEAD, Nq * Dq, nullptr, 0,
        W + OFF_PART, nullptr, PREDq,
        BMq, PREDq, 672, 672, (size_t)BMq * PREDq, 0, 0);
    head_reduce<<<(BMq * PREDq + 255) / 256, 256, 0, stream>>>(
        W + OFF_PART, head_b, W + OFF_HEAD);
    finalize_kernel<<<(Bq * PREDq * Mq + 255) / 256, 256, 0, stream>>>(
        W + OFF_HEAD, W + OFF_MEANS, W + OFF_STDS, out);
}

// Round 5
// 1689.908 us; speedup vs baseline: 2.6330x; 1.0625x over previous
//
#include <hip/hip_runtime.h>
#include <hip/hip_bf16.h>
#include <cstddef>

// ---- problem dims ----
#define Bq    16
#define Lq    512
#define Mq    32
#define PREDq 96
#define Pq    16
#define Sq    8
#define Dq    128
#define NSTq  16
#define DCq   4
#define NLq   4
#define Nq    63
#define DIq   256
#define DTRq  8
#define TOKq  32256   // 512*63 == 1008*32
#define BMq   512
#define BNq   1008

typedef __attribute__((ext_vector_type(8))) short short8;
typedef __attribute__((ext_vector_type(4))) float f32x4;
typedef __hip_bfloat16 bf16;

// ---- workspace layout (float offsets). total 54,578,176 floats = 218.3 MiB ----
constexpr size_t HSZ       = (size_t)TOKq * Dq;              // 4,128,768
constexpr size_t OFF_MEANS = 0;
constexpr size_t OFF_STDS  = 512;
constexpr size_t OFF_HEAD  = 1024;                           // 512*96 = 49152
constexpr size_t OFF_PART  = 50176;                          // 12 * 49152
constexpr size_t OFF_HIST  = 640000;                         // 9 * HSZ
constexpr size_t OFF_MIX   = OFF_HIST + 9 * HSZ;             // fp32 TOK*128
constexpr size_t OFF_XD    = OFF_MIX + HSZ;                  // fp32 TOK*40
constexpr size_t OFF_XZB   = OFF_XD + (size_t)TOKq * 40;     // bf16 TOK*512 (8,257,536 f)
constexpr size_t OFF_LNB   = OFF_XZB + (size_t)TOKq * 256;   // bf16 TOK*128 (2,064,384 f)
constexpr size_t OFF_WB    = OFF_LNB + (size_t)TOKq * 64;    // bf16 weights (1,038,336 f)
constexpr size_t WS_FLOATS = OFF_WB + 1038336;
// bf16-element offsets inside WB region:
constexpr size_t WBE_IN   = 0;           // 12*512*128 = 786432
constexpr size_t WBE_X    = 786432;      // 12*40*256  = 122880
constexpr size_t WBE_OUT  = 909312;      // 12*128*256 = 393216
constexpr size_t WBE_HEAD = 1302528;     // 96*8064    = 774144

__device__ __forceinline__ float silu_f(float v) { return v / (1.f + __expf(-v)); }

// ============ fp32 -> bf16 weight conversion ============
__global__ __launch_bounds__(256) void f2b_kernel(const float* __restrict__ s,
                                                  bf16* __restrict__ d, int n) {
    int i = blockIdx.x * 256 + threadIdx.x;
    if (i < n) d[i] = __float2bfloat16(s[i]);
}

// ============ stats: per (b,m) mean / unbiased std over L ============
__global__ __launch_bounds__(256) void stats_kernel(const float* __restrict__ x,
                                                    float* __restrict__ means,
                                                    float* __restrict__ stds) {
    int bm = blockIdx.x; int b = bm >> 5, m = bm & 31;
    int tid = threadIdx.x;
    float s = 0.f, ss = 0.f;
    for (int l = tid; l < Lq; l += 256) {
        float v = x[((size_t)b * Lq + l) * Mq + m];
        s += v; ss += v * v;
    }
#pragma unroll
    for (int o = 32; o >= 1; o >>= 1) { s += __shfl_xor(s, o); ss += __shfl_xor(ss, o); }
    __shared__ float sh0[4], sh1[4];
    if ((tid & 63) == 0) { sh0[tid >> 6] = s; sh1[tid >> 6] = ss; }
    __syncthreads();
    if (tid == 0) {
        float S  = sh0[0] + sh0[1] + sh0[2] + sh0[3];
        float SS = sh1[0] + sh1[1] + sh1[2] + sh1[3];
        float mean = S * (1.f / (float)Lq);
        float var  = (SS - (float)Lq * mean * mean) * (1.f / (float)(Lq - 1));
        means[bm] = mean;
        stds[bm]  = sqrtf(fmaxf(var, 0.f)) + 1e-5f;
    }
}

// ============ patch embed -> hist[0] (fp32) ============
__global__ __launch_bounds__(128) void patch_embed(const float* __restrict__ x,
                                                   const float* __restrict__ means,
                                                   const float* __restrict__ stds,
                                                   const float* __restrict__ pw,
                                                   const float* __restrict__ pb,
                                                   const float* __restrict__ pos,
                                                   float* __restrict__ h) {
    int blk = blockIdx.x;
    int bm = blk / Nq, n = blk - bm * Nq;
    int b = bm >> 5, m = bm & 31;
    int d = threadIdx.x;
    __shared__ float sx[Pq];
    if (d < Pq) {
        int l = n * Sq + d;
        sx[d] = (x[((size_t)b * Lq + l) * Mq + m] - means[bm]) / stds[bm];
    }
    __syncthreads();
    float acc = pb[d];
#pragma unroll
    for (int p = 0; p < Pq; p++) acc += sx[p] * pw[d * Pq + p];
    h[(size_t)blk * Dq + d] = acc + pos[n * Dq + d];
}

// ============ bf16 MFMA GEMM: C(M,N) = A(M,K) @ B(N,K)^T ============
// Tile 128(M) x 64(N) x 32(K), 4 waves. Split-K via gridDim.z.
__global__ __launch_bounds__(256) void gemm_bf16(
        const bf16* __restrict__ A, int lda,
        const bf16* __restrict__ Bw, int ldb,
        const float* __restrict__ resid, int ldr,
        float* __restrict__ C, bf16* __restrict__ Cb, int ldc,
        int M, int N, int Klen, int kstride, size_t c_split_stride,
        int accum, int rowmap) {
    __shared__ __align__(16) short Al[128 * 40];
    __shared__ __align__(16) short Bl[64 * 40];
    int tid = threadIdx.x;
    int wave = tid >> 6, lane = tid & 63;
    int m0 = blockIdx.y * 128, n0 = blockIdx.x * 64;
    int kbase = blockIdx.z * kstride;
    f32x4 acc[2][4];
#pragma unroll
    for (int i = 0; i < 2; i++)
#pragma unroll
        for (int j = 0; j < 4; j++) acc[i][j] = (f32x4){0.f, 0.f, 0.f, 0.f};

    int ar = tid >> 1, ah = tid & 1;
    int br = tid >> 2, bq2 = tid & 3;
    int mlane = lane & 15, koff = (lane >> 4) * 8;

    for (int k0 = 0; k0 < Klen; k0 += 32) {
        {
            const bf16* src = A + (size_t)(m0 + ar) * lda + kbase + k0 + ah * 16;
            uint4 v0 = *(const uint4*)src;
            uint4 v1 = *(const uint4*)(src + 8);
            *(uint4*)&Al[ar * 40 + ah * 16]     = v0;
            *(uint4*)&Al[ar * 40 + ah * 16 + 8] = v1;
        }
        {
            int gn = n0 + br;
            uint4 v = {0u, 0u, 0u, 0u};
            if (gn < N) v = *(const uint4*)(Bw + (size_t)gn * ldb + kbase + k0 + bq2 * 8);
            *(uint4*)&Bl[br * 40 + bq2 * 8] = v;
        }
        __syncthreads();
        short8 a0 = *(const short8*)&Al[(wave * 32 + mlane) * 40 + koff];
        short8 a1 = *(const short8*)&Al[(wave * 32 + 16 + mlane) * 40 + koff];
#pragma unroll
        for (int ns = 0; ns < 4; ns++) {
            short8 bfr = *(const short8*)&Bl[(ns * 16 + mlane) * 40 + koff];
            acc[0][ns] = __builtin_amdgcn_mfma_f32_16x16x32_bf16(a0, bfr, acc[0][ns], 0, 0, 0);
            acc[1][ns] = __builtin_amdgcn_mfma_f32_16x16x32_bf16(a1, bfr, acc[1][ns], 0, 0, 0);
        }
        __syncthreads();
    }

    float* Cz = C + (size_t)blockIdx.z * c_split_stride;
#pragma unroll
    for (int ms = 0; ms < 2; ms++) {
#pragma unroll
        for (int ns = 0; ns < 4; ns++) {
            int n = n0 + ns * 16 + mlane;
            if (n >= N) continue;
#pragma unroll
            for (int r = 0; r < 4; r++) {
                int m = m0 + wave * 32 + ms * 16 + (lane >> 4) * 4 + r;
                int orow = m;
                if (rowmap) {                       // (b*63+n)*32+m  ->  (b*32+m)*63+n
                    int bn = m >> 5, mm = m & 31;
                    int b = bn / Nq, nn = bn - b * Nq;
                    orow = (b * Mq + mm) * Nq + nn;
                }
                float v = acc[ms][ns][r];
                if (resid) v += resid[(size_t)orow * ldr + n];
                if (Cb) {
                    Cb[(size_t)orow * ldc + n] = __float2bfloat16(v);
                } else {
                    size_t o = (size_t)orow * ldc + n;
                    if (accum) Cz[o] += v; else Cz[o] = v;
                }
            }
        }
    }
}

// ============ head split-K reduce + bias ============
__global__ __launch_bounds__(256) void head_reduce(const float* __restrict__ part,
                                                   const float* __restrict__ bias,
                                                   float* __restrict__ out) {
    int i = blockIdx.x * 256 + threadIdx.x;
    if (i >= BMq * PREDq) return;
    float s = bias[i % PREDq];
#pragma unroll
    for (int z = 0; z < 12; z++) s += part[(size_t)z * BMq * PREDq + i];
    out[i] = s;
}

// ============ in-place causal depthwise conv (DC=4) + SiLU, bf16 xz cols 0..255 ============
__global__ __launch_bounds__(256) void conv_silu(bf16* __restrict__ xz,
                                                 const float* __restrict__ cw,
                                                 const float* __restrict__ cb,
                                                 int nb, int slen, int rev) {
    int idx = blockIdx.x * 256 + threadIdx.x;
    if (idx >= nb * DIq) return;
    int row = idx >> 8, c = idx & 255;
    float w0 = cw[c * 4 + 0], w1 = cw[c * 4 + 1], w2 = cw[c * 4 + 2], w3 = cw[c * 4 + 3];
    float bv = cb[c];
    float a = 0.f, bq = 0.f, cq = 0.f;
    if (!rev) {
        for (int s = 0; s < slen; s++) {
            size_t o = ((size_t)row * slen + s) * 512 + c;
            float xc = __bfloat162float(xz[o]);
            float v = w0 * a + w1 * bq + w2 * cq + w3 * xc + bv;
            xz[o] = __float2bfloat16(silu_f(v));
            a = bq; bq = cq; cq = xc;
        }
    } else {
        for (int s = slen - 1; s >= 0; s--) {
            size_t o = ((size_t)row * slen + s) * 512 + c;
            float xc = __bfloat162float(xz[o]);
            float v = w0 * a + w1 * bq + w2 * cq + w3 * xc + bv;
            xz[o] = __float2bfloat16(silu_f(v));
            a = bq; bq = cq; cq = xc;
        }
    }
}

// ============ fused dt_proj + softplus + scan + D skip + z gate ============
// v3: whole-row xd in LDS; u/z chunked register double-buffer (8 steps/chunk,
// prefetch next chunk -> ~8-step latency slack); decay-by-powers fast path
// (A_log = log(1..16) broadcast => exp(dt*A[j]) = p^(j+1), checked at runtime).
template<int SLEN>
__global__ __launch_bounds__(256) void scan_kernel_t(bf16* __restrict__ xz,
                                                     const float* __restrict__ xd,
                                                     const float* __restrict__ dtw,
                                                     const float* __restrict__ dtb,
                                                     const float* __restrict__ alog,
                                                     const float* __restrict__ Dp,
                                                     int rev) {
    __shared__ __align__(16) float sxd[SLEN * 40];
    int row = blockIdx.x;
    int d = threadIdx.x;
    const float* src = xd + (size_t)row * SLEN * 40;
    for (int i = d; i < SLEN * 40; i += 256) sxd[i] = src[i];
    __syncthreads();

    float A2[16], h[16];
    bool fast = true;
#pragma unroll
    for (int j = 0; j < 16; j++) {
        A2[j] = -__expf(alog[d * 16 + j]);
        h[j] = 0.f;
        fast = fast && (fabsf(A2[j] - A2[0] * (float)(j + 1)) < 1e-5f * (float)(j + 1));
    }
    float dw[8];
#pragma unroll
    for (int r = 0; r < 8; r++) dw[r] = dtw[d * 8 + r];
    float dbv = dtb[d], Dv = Dp[d];

    size_t base = (size_t)row * SLEN * 512 + d;
    constexpr int NCH = (SLEN + 7) / 8;

    float ucur[8], zcur[8], unxt[8], znxt[8];
#pragma unroll
    for (int i = 0; i < 8; i++) {                       // load chunk 0
        int st = i < SLEN ? i : SLEN - 1;
        int s = rev ? (SLEN - 1 - st) : st;
        size_t o = base + (size_t)s * 512;
        ucur[i] = __bfloat162float(xz[o]);
        zcur[i] = __bfloat162float(xz[o + 256]);
    }

    for (int c = 0; c < NCH; c++) {
        if (c + 1 < NCH) {                              // prefetch next chunk
#pragma unroll
            for (int i = 0; i < 8; i++) {
                int st = (c + 1) * 8 + i; st = st < SLEN ? st : SLEN - 1;
                int s = rev ? (SLEN - 1 - st) : st;
                size_t o = base + (size_t)s * 512;
                unxt[i] = __bfloat162float(xz[o]);
                znxt[i] = __bfloat162float(xz[o + 256]);
            }
        }
#pragma unroll
        for (int i = 0; i < 8; i++) {
            int st = c * 8 + i;
            if (st < SLEN) {
                int s = rev ? (SLEN - 1 - st) : st;
                const float4* q = (const float4*)(sxd + s * 40);
                float4 q0 = q[0], q1 = q[1];
                float dtv = dbv + dw[0]*q0.x + dw[1]*q0.y + dw[2]*q0.z + dw[3]*q0.w
                                + dw[4]*q1.x + dw[5]*q1.y + dw[6]*q1.z + dw[7]*q1.w;
                dtv = fmaxf(dtv, 0.f) + __logf(1.f + __expf(-fabsf(dtv)));   // softplus
                float Bv[16], Cv[16];
                *(float4*)&Bv[0]  = q[2]; *(float4*)&Bv[4]  = q[3];
                *(float4*)&Bv[8]  = q[4]; *(float4*)&Bv[12] = q[5];
                *(float4*)&Cv[0]  = q[6]; *(float4*)&Cv[4]  = q[7];
                *(float4*)&Cv[8]  = q[8]; *(float4*)&Cv[12] = q[9];
                float uv = ucur[i], zv = zcur[i];
                float du = dtv * uv;
                float y = 0.f;
                if (fast) {
                    float p = __expf(dtv * A2[0]);
                    float e = p;
#pragma unroll
                    for (int j = 0; j < 16; j++) {
                        h[j] = h[j] * e + du * Bv[j];
                        y += h[j] * Cv[j];
                        e *= p;
                    }
                } else {
#pragma unroll
                    for (int j = 0; j < 16; j++) {
                        float e = __expf(dtv * A2[j]);
                        h[j] = h[j] * e + du * Bv[j];
                        y += h[j] * Cv[j];
                    }
                }
                xz[base + (size_t)s * 512] = __float2bfloat16((y + uv * Dv) * silu_f(zv));
            }
        }
#pragma unroll
        for (int i = 0; i < 8; i++) { ucur[i] = unxt[i]; zcur[i] = znxt[i]; }
    }
}

// ============ token mix + LN (MIX fp32, LN out bf16) ============
__global__ __launch_bounds__(64) void mix_ln_tok(float* __restrict__ W, bf16* __restrict__ lnb_out,
                                                 const float* __restrict__ alpha,
                                                 const float* __restrict__ beta,
                                                 const float* __restrict__ lnw,
                                                 const float* __restrict__ lnb, int l) {
    int t = blockIdx.x, d = threadIdx.x;
    int cnt = l + 1;
    float aw[4], bw[4];
    float amax = -1e30f, bmax = -1e30f;
    for (int i = 0; i < cnt; i++) {
        aw[i] = alpha[l * 4 + i]; bw[i] = beta[l * 4 + i];
        amax = fmaxf(amax, aw[i]); bmax = fmaxf(bmax, bw[i]);
    }
    float as = 0.f, bs = 0.f;
    for (int i = 0; i < cnt; i++) {
        aw[i] = __expf(aw[i] - amax); as += aw[i];
        bw[i] = __expf(bw[i] - bmax); bs += bw[i];
    }
    float ai = 1.f / as, bi = 1.f / bs;
    float v0 = 0.f, v1 = 0.f;
    for (int i = 0; i < cnt; i++) {
        const float* yt = W + OFF_HIST + (size_t)(i == 0 ? 0 : i) * HSZ + (size_t)t * 128;
        const float* yc = W + OFF_HIST + (size_t)(i == 0 ? 0 : 4 + i) * HSZ + (size_t)t * 128;
        float wa = aw[i] * ai, wb = bw[i] * bi;
        v0 += wa * yt[d]      + wb * yc[d];
        v1 += wa * yt[d + 64] + wb * yc[d + 64];
    }
    float* mix = W + OFF_MIX + (size_t)t * 128;
    mix[d] = v0; mix[d + 64] = v1;
    float s = v0 + v1, ss = v0 * v0 + v1 * v1;
#pragma unroll
    for (int o = 32; o >= 1; o >>= 1) { s += __shfl_xor(s, o); ss += __shfl_xor(ss, o); }
    float mean = s * (1.f / 128.f);
    float var  = ss * (1.f / 128.f) - mean * mean;
    float rstd = rsqrtf(var + 1e-5f);
    bf16* lo = lnb_out + (size_t)t * 128;
    lo[d]      = __float2bfloat16((v0 - mean) * rstd * lnw[d]      + lnb[d]);
    lo[d + 64] = __float2bfloat16((v1 - mean) * rstd * lnw[d + 64] + lnb[d + 64]);
}

// ============ channel mix + LN + transpose (LN out bf16, channel layout) ============
__global__ __launch_bounds__(64) void mix_ln_ch(float* __restrict__ W, bf16* __restrict__ lnb_out,
                                                const float* __restrict__ theta,
                                                const float* __restrict__ gamma,
                                                const float* __restrict__ lnw,
                                                const float* __restrict__ lnb, int l) {
    int t = blockIdx.x, d = threadIdx.x;
    int ct = l + 2, cg = l + 1;
    float tw[5], gw[4];
    float tmax = -1e30f, gmax = -1e30f;
    for (int i = 0; i < ct; i++) { tw[i] = theta[l * 5 + i]; tmax = fmaxf(tmax, tw[i]); }
    for (int i = 0; i < cg; i++) { gw[i] = gamma[l * 4 + i]; gmax = fmaxf(gmax, gw[i]); }
    float ts = 0.f, gs = 0.f;
    for (int i = 0; i < ct; i++) { tw[i] = __expf(tw[i] - tmax); ts += tw[i]; }
    for (int i = 0; i < cg; i++) { gw[i] = __expf(gw[i] - gmax); gs += gw[i]; }
    float ti = 1.f / ts, gi = 1.f / gs;
    float v0 = 0.f, v1 = 0.f;
    for (int i = 0; i < ct; i++) {
        const float* yt = W + OFF_HIST + (size_t)(i == 0 ? 0 : i) * HSZ + (size_t)t * 128;
        float w_ = tw[i] * ti;
        v0 += w_ * yt[d]; v1 += w_ * yt[d + 64];
    }
    for (int i = 0; i < cg; i++) {
        const float* yc = W + OFF_HIST + (size_t)(i == 0 ? 0 : 4 + i) * HSZ + (size_t)t * 128;
        float w_ = gw[i] * gi;
        v0 += w_ * yc[d]; v1 += w_ * yc[d + 64];
    }
    float* mix = W + OFF_MIX + (size_t)t * 128;
    mix[d] = v0; mix[d + 64] = v1;
    float s = v0 + v1, ss = v0 * v0 + v1 * v1;
#pragma unroll
    for (int o = 32; o >= 1; o >>= 1) { s += __shfl_xor(s, o); ss += __shfl_xor(ss, o); }
    float mean = s * (1.f / 128.f);
    float var  = ss * (1.f / 128.f) - mean * mean;
    float rstd = rsqrtf(var + 1e-5f);
    int bm = t / Nq, n = t - bm * Nq, b = bm >> 5, m = bm & 31;
    bf16* lo = lnb_out + (size_t)((b * Nq + n) * Mq + m) * 128;
    lo[d]      = __float2bfloat16((v0 - mean) * rstd * lnw[d]      + lnb[d]);
    lo[d + 64] = __float2bfloat16((v1 - mean) * rstd * lnw[d + 64] + lnb[d + 64]);
}

// ============ channel residual: hist[5+l] += MIX ============
__global__ __launch_bounds__(128) void combine_ch(float* __restrict__ W, int l) {
    size_t i = (size_t)blockIdx.x * 128 + threadIdx.x;
    W[OFF_HIST + (size_t)(5 + l) * HSZ + i] += W[OFF_MIX + i];
}

// ============ plain LN over D=128 (fp32 out) ============
__global__ __launch_bounds__(64) void ln128_kernel(const float* __restrict__ in,
                                                   const float* __restrict__ w,
                                                   const float* __restrict__ b,
                                                   float* __restrict__ out) {
    int t = blockIdx.x, d = threadIdx.x;
    float v0 = in[(size_t)t * 128 + d], v1 = in[(size_t)t * 128 + d + 64];
    float s = v0 + v1, ss = v0 * v0 + v1 * v1;
#pragma unroll
    for (int o = 32; o >= 1; o >>= 1) { s += __shfl_xor(s, o); ss += __shfl_xor(ss, o); }
    float mean = s * (1.f / 128.f);
    float var  = ss * (1.f / 128.f) - mean * mean;
    float rstd = rsqrtf(var + 1e-5f);
    out[(size_t)t * 128 + d]      = (v0 - mean) * rstd * w[d]      + b[d];
    out[(size_t)t * 128 + d + 64] = (v1 - mean) * rstd * w[d + 64] + b[d + 64];
}

// ============ LN over N=63 (per (bm,d)), bf16 out ============
__global__ __launch_bounds__(256) void final_ln2(const float* __restrict__ in,
                                                 const float* __restrict__ w2,
                                                 const float* __restrict__ b2,
                                                 bf16* __restrict__ out) {
    int idx = blockIdx.x * 256 + threadIdx.x;
    if (idx >= BMq * Dq) return;
    int bm = idx >> 7, d = idx & 127;
    float s = 0.f, ss = 0.f;
    for (int n = 0; n < Nq; n++) {
        float v = in[((size_t)bm * Nq + n) * 128 + d];
        s += v; ss += v * v;
    }
    float mean = s * (1.f / (float)Nq);
    float var  = ss * (1.f / (float)Nq) - mean * mean;
    float rstd = rsqrtf(var + 1e-5f);
    for (int n = 0; n < Nq; n++) {
        float v = in[((size_t)bm * Nq + n) * 128 + d];
        out[((size_t)bm * Nq + n) * 128 + d] = __float2bfloat16((v - mean) * rstd * w2[n] + b2[n]);
    }
}

// ============ final rescale & transpose ============
__global__ __launch_bounds__(256) void finalize_kernel(const float* __restrict__ ht,
                                                       const float* __restrict__ means,
                                                       const float* __restrict__ stds,
                                                       float* __restrict__ out) {
    int idx = blockIdx.x * 256 + threadIdx.x;
    if (idx >= Bq * PREDq * Mq) return;
    int b = idx / (PREDq * Mq);
    int r = idx - b * PREDq * Mq;
    int pr = r >> 5, m = r & 31;
    int bm = b * Mq + m;
    out[idx] = ht[(size_t)bm * PREDq + pr] * stds[bm] + means[bm];
}

// ============ host-side mamba driver ============
static void run_mamba(hipStream_t stream, float* W, const bf16* lnb_in,
                      const float* resid, float* dst, int accum, int rowmap,
                      const bf16* wb_in, const float* cw, const float* cb,
                      const bf16* wb_x, const float* dtw, const float* dtb,
                      const float* alog, const float* Dp, const bf16* wb_out,
                      int nb, int slen, int rev) {
    bf16* xz = (bf16*)(W + OFF_XZB);
    gemm_bf16<<<dim3(8, 252, 1), 256, 0, stream>>>(
        lnb_in, 128, wb_in, 128, nullptr, 0, nullptr, xz, 512,
        TOKq, 512, 128, 0, 0, 0, 0);
    conv_silu<<<(nb * DIq + 255) / 256, 256, 0, stream>>>(xz, cw, cb, nb, slen, rev);
    gemm_bf16<<<dim3(1, 252, 1), 256, 0, stream>>>(
        xz, 512, wb_x, 256, nullptr, 0, W + OFF_XD, nullptr, 40,
        TOKq, 40, 256, 0, 0, 0, 0);
    if (slen == Nq)
        scan_kernel_t<Nq><<<nb, 256, 0, stream>>>(xz, W + OFF_XD, dtw, dtb, alog, Dp, rev);
    else
        scan_kernel_t<Mq><<<nb, 256, 0, stream>>>(xz, W + OFF_XD, dtw, dtb, alog, Dp, rev);
    gemm_bf16<<<dim3(2, 252, 1), 256, 0, stream>>>(
        xz, 512, wb_out, 256, resid, 128, dst, nullptr, 128,
        TOKq, 128, 256, 0, 0, accum, rowmap);
}

extern "C" void kernel_launch(void* const* d_in, const int* in_sizes, int n_in,
                              void* d_out, int out_size, void* d_ws, size_t ws_size,
                              hipStream_t stream) {
    if (ws_size < WS_FLOATS * sizeof(float)) return;

    const float* x          = (const float*)d_in[0];
    const float* patch_w    = (const float*)d_in[1];
    const float* patch_b    = (const float*)d_in[2];
    const float* pos_embed  = (const float*)d_in[3];
    const float* alpha      = (const float*)d_in[4];
    const float* beta       = (const float*)d_in[5];
    const float* theta      = (const float*)d_in[6];
    const float* gamma      = (const float*)d_in[7];
    const float* tok_norm_w = (const float*)d_in[8];
    const float* tok_norm_b = (const float*)d_in[9];
    const float* ch_norm_w  = (const float*)d_in[10];
    const float* ch_norm_b  = (const float*)d_in[11];
    const float* in_proj_w  = (const float*)d_in[12];
    const float* conv_w     = (const float*)d_in[13];
    const float* conv_b     = (const float*)d_in[14];
    const float* x_proj_w   = (const float*)d_in[15];
    const float* dt_proj_w  = (const float*)d_in[16];
    const float* dt_proj_b  = (const float*)d_in[17];
    const float* A_log      = (const float*)d_in[18];
    const float* D_ssm      = (const float*)d_in[19];
    const float* out_proj_w = (const float*)d_in[20];
    const float* n2d_w1     = (const float*)d_in[21];
    const float* n2d_b1     = (const float*)d_in[22];
    const float* n2d_w2     = (const float*)d_in[23];
    const float* n2d_b2     = (const float*)d_in[24];
    const float* head_w     = (const float*)d_in[25];
    const float* head_b     = (const float*)d_in[26];

    float* W   = (float*)d_ws;
    float* out = (float*)d_out;
    bf16* WB   = (bf16*)(W + OFF_WB);
    bf16* LNB  = (bf16*)(W + OFF_LNB);

    f2b_kernel<<<(786432 + 255) / 256, 256, 0, stream>>>(in_proj_w,  WB + WBE_IN,   786432);
    f2b_kernel<<<(122880 + 255) / 256, 256, 0, stream>>>(x_proj_w,   WB + WBE_X,    122880);
    f2b_kernel<<<(393216 + 255) / 256, 256, 0, stream>>>(out_proj_w, WB + WBE_OUT,  393216);
    f2b_kernel<<<(774144 + 255) / 256, 256, 0, stream>>>(head_w,     WB + WBE_HEAD, 774144);

    stats_kernel<<<BMq, 256, 0, stream>>>(x, W + OFF_MEANS, W + OFF_STDS);
    patch_embed<<<TOKq, 128, 0, stream>>>(x, W + OFF_MEANS, W + OFF_STDS,
                                          patch_w, patch_b, pos_embed, W + OFF_HIST);

    for (int l = 0; l < NLq; l++) {
        // ---- token mamba ----
        mix_ln_tok<<<TOKq, 64, 0, stream>>>(W, LNB, alpha, beta,
                                            tok_norm_w + l * Dq, tok_norm_b + l * Dq, l);
        {
            size_t o = (size_t)(l * 3 + 0);
            run_mamba(stream, W, LNB, W + OFF_MIX,
                      W + OFF_HIST + (size_t)(1 + l) * HSZ, 0, 0,
                      WB + WBE_IN + o * 512 * 128, conv_w + o * 256 * 4, conv_b + o * 256,
                      WB + WBE_X + o * 40 * 256, dt_proj_w + o * 256 * 8, dt_proj_b + o * 256,
                      A_log + o * 256 * 16, D_ssm + o * 256, WB + WBE_OUT + o * 128 * 256,
                      BMq, Nq, 0);
        }
        // ---- channel mamba (bidirectional) -> hist[5+l] ----
        mix_ln_ch<<<TOKq, 64, 0, stream>>>(W, LNB, theta, gamma,
                                           ch_norm_w + l * Dq, ch_norm_b + l * Dq, l);
        {
            size_t o = (size_t)(l * 3 + 1);
            run_mamba(stream, W, LNB, nullptr,
                      W + OFF_HIST + (size_t)(5 + l) * HSZ, 0, 1,
                      WB + WBE_IN + o * 512 * 128, conv_w + o * 256 * 4, conv_b + o * 256,
                      WB + WBE_X + o * 40 * 256, dt_proj_w + o * 256 * 8, dt_proj_b + o * 256,
                      A_log + o * 256 * 16, D_ssm + o * 256, WB + WBE_OUT + o * 128 * 256,
                      BNq, Mq, 0);
        }
        {
            size_t o = (size_t)(l * 3 + 2);
            run_mamba(stream, W, LNB, nullptr,
                      W + OFF_HIST + (size_t)(5 + l) * HSZ, 1, 1,
                      WB + WBE_IN + o * 512 * 128, conv_w + o * 256 * 4, conv_b + o * 256,
                      WB + WBE_X + o * 40 * 256, dt_proj_w + o * 256 * 8, dt_proj_b + o * 256,
                      A_log + o * 256 * 16, D_ssm + o * 256, WB + WBE_OUT + o * 128 * 256,
                      BNq, Mq, 1);
        }
        combine_ch<<<TOKq, 128, 0, stream>>>(W, l);
    }

    // ---- Norm2D + head ----
    ln128_kernel<<<TOKq, 64, 0, stream>>>(W + OFF_HIST + 8 * HSZ, n2d_w1, n2d_b1, W + OFF_MIX);
    final_ln2<<<(BMq * Dq + 255) / 256, 256, 0, stream>>>(W + OFF_MIX, n2d_w2, n2d_b2, LNB);
    gemm_bf16<<<dim3(2, 4, 12), 256, 0, stream>>>(
        LNB, Nq * Dq, WB + WBE_HEAD, Nq * Dq, nullptr, 0,
        W + OFF_PART, nullptr, PREDq,
        BMq, PREDq, 672, 672, (size_t)BMq * PREDq, 0, 0);
    head_reduce<<<(BMq * PREDq + 255) / 256, 256, 0, stream>>>(
        W + OFF_PART, head_b, W + OFF_HEAD);
    finalize_kernel<<<(Bq * PREDq * Mq + 255) / 256, 256, 0, stream>>>(
        W + OFF_HEAD, W + OFF_MEANS, W + OFF_STDS, out);
}